// Round 9
// baseline (2577.268 us; speedup 1.0000x reference)
//
#include <hip/hip_runtime.h>
#include <hip/hip_bf16.h>
#include <cstdint>
#include <cstring>

#define NN 100000
#define NE 1600000
#define HID 64
#define EPS 1e-5f

typedef __bf16 bf16_t;
typedef __attribute__((ext_vector_type(8))) __bf16 bf16x8;
typedef __attribute__((ext_vector_type(4))) float f32x4;
typedef __attribute__((ext_vector_type(2))) float f32x2;
typedef __attribute__((ext_vector_type(16))) float f32x16;

#define LDS_FENCE() asm volatile("s_waitcnt lgkmcnt(0)" ::: "memory")

// ---------------- dtype detectors ----------------
__global__ void k_detect(const unsigned* __restrict__ xw, const int* __restrict__ eiw,
                         int* __restrict__ flags) {
  int lane = threadIdx.x;  // 64
  unsigned u = xw[lane];
  unsigned lo = u & 0xFFFFu;
  unsigned e = (lo >> 7) & 0xFFu;
  bool bf_ok = (lo == 0u) || (e >= 0x50u && e <= 0x8Fu);
  unsigned long long b1 = __ballot(bf_ok);
  int v = eiw[2 * lane + 1];
  unsigned long long b2 = __ballot(v == 0);
  if (lane == 0) {
    flags[0] = (b1 == ~0ull) ? 1 : 0;
    flags[1] = (b2 == ~0ull) ? 1 : 0;
  }
}

// ---------------- input canonicalization ----------------
struct FPtrs {
  const void* p[17];
  int len[17];
  int ofs[17];
};

template <typename FT>
__global__ void k_cvt_f(FPtrs fp, float* __restrict__ canon, const int* __restrict__ flags,
                        int total) {
  if (flags[0] != (int)(sizeof(FT) == 2)) return;
  int i = blockIdx.x * blockDim.x + threadIdx.x;
  int stride = gridDim.x * blockDim.x;
  for (int t = i; t < total; t += stride) {
    int seg = 0;
    while (seg < 16 && t >= fp.ofs[seg] + fp.len[seg]) ++seg;
    canon[t] = (float)((const FT*)fp.p[seg])[t - fp.ofs[seg]];
  }
}

template <typename IT>
__global__ void k_cvt_idx(const IT* __restrict__ ei, int* __restrict__ eic,
                          const int* __restrict__ flags) {
  if (flags[1] != (int)(sizeof(IT) == 8)) return;
  int i = blockIdx.x * blockDim.x + threadIdx.x;
  int stride = gridDim.x * blockDim.x;
  for (int t = i; t < 2 * NE; t += stride) eic[t] = (int)ei[t];
}

// ---------------- utility: zero fill ----------------
__global__ void k_zero4(f32x4* __restrict__ p, int n4) {
  int i = blockIdx.x * blockDim.x + threadIdx.x;
  int stride = gridDim.x * blockDim.x;
  f32x4 z = {0.f, 0.f, 0.f, 0.f};
  for (int t = i; t < n4; t += stride) p[t] = z;
}

// ---------------- CSR build (dst-major, for GCN gather) ----------------
__global__ void k_count(const int* __restrict__ col, int* __restrict__ cnt) {
  int i = blockIdx.x * blockDim.x + threadIdx.x;
  int stride = gridDim.x * blockDim.x;
  for (int e = i; e < NE; e += stride) atomicAdd(&cnt[col[e]], 1);
}

__global__ void k_dinv(const int* __restrict__ cnt, float* __restrict__ d) {
  int n = blockIdx.x * blockDim.x + threadIdx.x;
  if (n < NN) d[n] = rsqrtf((float)cnt[n] + 1.0f);  // self-loop
}

__global__ void k_scan1(const int* __restrict__ cnt, int* __restrict__ rowptr,
                        int* __restrict__ bsum, int nvals) {
  __shared__ int tmp[256];
  int gid = blockIdx.x * 256 + threadIdx.x;
  int v = (gid < nvals) ? cnt[gid] : 0;
  tmp[threadIdx.x] = v;
  __syncthreads();
  for (int s = 1; s < 256; s <<= 1) {
    int add = (threadIdx.x >= s) ? tmp[threadIdx.x - s] : 0;
    __syncthreads();
    tmp[threadIdx.x] += add;
    __syncthreads();
  }
  if (gid < nvals) rowptr[gid] = tmp[threadIdx.x] - v;
  if (threadIdx.x == 255) bsum[blockIdx.x] = tmp[255];
}

__global__ void k_scan2(int* __restrict__ bsum, int* __restrict__ btop, int nblocks) {
  __shared__ int tmp[512];
  int v = (threadIdx.x < nblocks) ? bsum[threadIdx.x] : 0;
  tmp[threadIdx.x] = v;
  __syncthreads();
  for (int s = 1; s < 512; s <<= 1) {
    int add = (threadIdx.x >= s) ? tmp[threadIdx.x - s] : 0;
    __syncthreads();
    tmp[threadIdx.x] += add;
    __syncthreads();
  }
  if (threadIdx.x < nblocks) btop[threadIdx.x] = tmp[threadIdx.x] - v;
}

__global__ void k_scan3(int* __restrict__ rowptr, const int* __restrict__ btop,
                        int* __restrict__ cursor, int nvals) {
  int gid = blockIdx.x * 256 + threadIdx.x;
  if (gid < nvals) {
    int v = rowptr[gid] + btop[blockIdx.x];
    rowptr[gid] = v;
    cursor[gid] = v;
  }
}

__global__ void k_fill(const int* __restrict__ eic, int* __restrict__ cursor,
                       int* __restrict__ csr_src) {
  int i = blockIdx.x * blockDim.x + threadIdx.x;
  int stride = gridDim.x * blockDim.x;
  for (int e = i; e < NE; e += stride) {
    int src = eic[e], dst = eic[NE + e];
    int pos = atomicAdd(&cursor[dst], 1);
    csr_src[pos] = src;
  }
}

// ---------------- layer 1: hs = (x @ W1) * dinv ----------------
__global__ void k_xw1(const float* __restrict__ x, const float* __restrict__ W1,
                      const float* __restrict__ dinv, float* __restrict__ hs) {
  int gid = blockIdx.x * blockDim.x + threadIdx.x;
  if (gid >= NN * HID) return;
  int n = gid >> 6, j = gid & 63;
  float acc = x[n * 3 + 0] * W1[0 * 64 + j] + x[n * 3 + 1] * W1[1 * 64 + j] +
              x[n * 3 + 2] * W1[2 * 64 + j];
  hs[gid] = acc * dinv[n];
}

// ---------------- hs = (h @ W) * dinv ----------------
__global__ __launch_bounds__(256) void k_hw(const float* __restrict__ h,
                                            const float* __restrict__ W,
                                            const float* __restrict__ dinv,
                                            float* __restrict__ hs) {
  __shared__ float Wl[64 * 64];
  __shared__ float hrow[4][64];
  int tid = threadIdx.x;
  for (int i = tid; i < 64 * 64; i += 256) Wl[i] = W[i];
  __syncthreads();
  int w = tid >> 6, j = tid & 63;
  for (int nb = blockIdx.x * 4 + w; nb < NN; nb += gridDim.x * 4) {
    hrow[w][j] = h[nb * 64 + j];
    LDS_FENCE();
    float acc = 0.f;
#pragma unroll 8
    for (int k = 0; k < 64; ++k) acc += hrow[w][k] * Wl[k * 64 + j];
    hs[nb * 64 + j] = acc * dinv[nb];
  }
}

// ---------------- gather-aggregate + fused finalize ----------------
template <bool RELU>
__global__ __launch_bounds__(256) void k_gather(const int* __restrict__ rowptr,
                                                const int* __restrict__ cnt,
                                                const int* __restrict__ csr_src,
                                                const float* __restrict__ hs,
                                                const float* __restrict__ dinv,
                                                const float* __restrict__ b,
                                                float* __restrict__ outf) {
  int wid = (blockIdx.x * blockDim.x + threadIdx.x) >> 6;
  int nw = (gridDim.x * blockDim.x) >> 6;
  int j = threadIdx.x & 63;
  for (int n = wid; n < NN; n += nw) {
    int beg = rowptr[n], c = cnt[n];
    float acc = hs[n * 64 + j];  // self-loop
    int k = 0;
    for (; k + 8 <= c; k += 8) {
      int s0 = csr_src[beg + k + 0], s1 = csr_src[beg + k + 1];
      int s2 = csr_src[beg + k + 2], s3 = csr_src[beg + k + 3];
      int s4 = csr_src[beg + k + 4], s5 = csr_src[beg + k + 5];
      int s6 = csr_src[beg + k + 6], s7 = csr_src[beg + k + 7];
      float v0 = hs[s0 * 64 + j], v1 = hs[s1 * 64 + j];
      float v2 = hs[s2 * 64 + j], v3 = hs[s3 * 64 + j];
      float v4 = hs[s4 * 64 + j], v5 = hs[s5 * 64 + j];
      float v6 = hs[s6 * 64 + j], v7 = hs[s7 * 64 + j];
      acc += ((v0 + v1) + (v2 + v3)) + ((v4 + v5) + (v6 + v7));
    }
    for (; k < c; ++k) acc += hs[csr_src[beg + k] * 64 + j];
    float v = acc * dinv[n] + b[j];
    outf[n * 64 + j] = RELU ? fmaxf(v, 0.f) : v;
  }
}

// ---------------- node-level factorization: u = h3@Wm1_top, v = h3@Wm1_bot ----------------
__global__ __launch_bounds__(256) void k_uv(const float* __restrict__ h3,
                                            const float* __restrict__ Wm1f,
                                            bf16_t* __restrict__ u, bf16_t* __restrict__ v) {
  __shared__ float Wt[64 * 64];
  __shared__ float Wb[64 * 64];
  __shared__ float hrow[4][64];
  int tid = threadIdx.x;
  for (int i = tid; i < 64 * 64; i += 256) {
    Wt[i] = Wm1f[i];
    Wb[i] = Wm1f[4096 + i];
  }
  __syncthreads();
  int w = tid >> 6, j = tid & 63;
  for (int nb = blockIdx.x * 4 + w; nb < NN; nb += gridDim.x * 4) {
    hrow[w][j] = h3[nb * 64 + j];
    LDS_FENCE();
    float au = 0.f, av = 0.f;
#pragma unroll 8
    for (int k = 0; k < 64; ++k) {
      float hv = hrow[w][k];
      au += hv * Wt[k * 64 + j];
      av += hv * Wb[k * 64 + j];
    }
    u[nb * 64 + j] = (bf16_t)au;
    v[nb * 64 + j] = (bf16_t)av;
  }
}

// ============ pass 1: BN1 stats of a1 = relu(u[src]+v[dst]+bm1) ============
// All 16-wide per-lane data in f32x16 ext-vectors (SSA registers — no scratch spill).
__global__ __launch_bounds__(256) void k_e1(const int* __restrict__ eic,
                                            const bf16_t* __restrict__ u,
                                            const bf16_t* __restrict__ v,
                                            const float* __restrict__ bm1f,
                                            float* __restrict__ sum1,
                                            float* __restrict__ sq1) {
  int lane = threadIdx.x & 63;
  int wave = blockIdx.x * 4 + (threadIdx.x >> 6);
  int nwaves = gridDim.x * 4;
  int n = lane & 15, q = lane >> 4;
  f32x16 bk;
#pragma unroll
  for (int j = 0; j < 8; ++j) {
    bk[j] = bm1f[q * 8 + j];
    bk[8 + j] = bm1f[32 + q * 8 + j];
  }
  f32x16 accs = {};
  f32x16 accq = {};
#pragma unroll 2
  for (int t = wave; t < NE / 16; t += nwaves) {
    int e = t * 16 + n;
    int src = eic[e], dst = eic[NE + e];
    const bf16x8* pu = (const bf16x8*)(u + src * 64);
    const bf16x8* pv = (const bf16x8*)(v + dst * 64);
    bf16x8 ua = pu[q], ub = pu[4 + q], va = pv[q], vb = pv[4 + q];
    f32x16 a1k;
#pragma unroll
    for (int j = 0; j < 8; ++j) {
      a1k[j] = fmaxf((float)ua[j] + (float)va[j] + bk[j], 0.f);
      a1k[8 + j] = fmaxf((float)ub[j] + (float)vb[j] + bk[8 + j], 0.f);
    }
    accs += a1k;
    accq += a1k * a1k;
  }
  // reduce over n (lane bits 0-3); lane n==0 of each q-group holds 16 distinct columns
#pragma unroll
  for (int j = 0; j < 16; ++j) {
    float s = accs[j], qq = accq[j];
    s += __shfl_xor(s, 1); s += __shfl_xor(s, 2);
    s += __shfl_xor(s, 4); s += __shfl_xor(s, 8);
    qq += __shfl_xor(qq, 1); qq += __shfl_xor(qq, 2);
    qq += __shfl_xor(qq, 4); qq += __shfl_xor(qq, 8);
    if (n == 0) {
      int col = (j < 8) ? (q * 8 + j) : (32 + q * 8 + (j - 8));
      unsafeAtomicAdd(&sum1[col], s);
      unsafeAtomicAdd(&sq1[col], qq);
    }
  }
}

// ---------------- BN affine constants ----------------
__global__ void k_bnconst(const float* __restrict__ sum, const float* __restrict__ sq,
                          const float* __restrict__ g, const float* __restrict__ be,
                          float* __restrict__ sarr, float* __restrict__ tarr, int ncol) {
  int j = threadIdx.x;
  if (j >= ncol) return;
  float mu = sum[j] / (float)NE;
  float var = fmaxf(sq[j] / (float)NE - mu * mu, 0.f);
  float s = g[j] * rsqrtf(var + EPS);
  sarr[j] = s;
  tarr[j] = be[j] - mu * s;
}

// ============ pass 2: BN2 stats of a2 (+ optional store of pre-BN a2) ============
template <bool STORE>
__global__ __launch_bounds__(256) void k_e2(const int* __restrict__ eic,
                                            const bf16_t* __restrict__ u,
                                            const bf16_t* __restrict__ v,
                                            const float* __restrict__ bm1f,
                                            const float* __restrict__ s1, const float* __restrict__ t1,
                                            const float* __restrict__ Wm2f,
                                            const float* __restrict__ bm2f,
                                            bf16_t* __restrict__ a2s,
                                            float* __restrict__ sum2,
                                            float* __restrict__ sq2) {
  int lane = threadIdx.x & 63;
  int wave = blockIdx.x * 4 + (threadIdx.x >> 6);
  int nwaves = gridDim.x * 4;
  int n = lane & 15, q = lane >> 4;
  f32x16 bk, s1k, t1k;
#pragma unroll
  for (int j = 0; j < 8; ++j) {
    bk[j] = bm1f[q * 8 + j];       bk[8 + j] = bm1f[32 + q * 8 + j];
    s1k[j] = s1[q * 8 + j];        s1k[8 + j] = s1[32 + q * 8 + j];
    t1k[j] = t1[q * 8 + j];        t1k[8 + j] = t1[32 + q * 8 + j];
  }
  bf16x8 b2h00, b2h01, b2h10, b2h11;
#pragma unroll
  for (int j = 0; j < 8; ++j) {
    b2h00[j] = (bf16_t)Wm2f[(q * 8 + j) * 32 + 0 * 16 + n];
    b2h01[j] = (bf16_t)Wm2f[(q * 8 + j) * 32 + 1 * 16 + n];
    b2h10[j] = (bf16_t)Wm2f[(32 + q * 8 + j) * 32 + 0 * 16 + n];
    b2h11[j] = (bf16_t)Wm2f[(32 + q * 8 + j) * 32 + 1 * 16 + n];
  }
  float bias20 = bm2f[n], bias21 = bm2f[16 + n];
  float accs0 = 0.f, accs1 = 0.f, accq0 = 0.f, accq1 = 0.f;
  for (int t = wave; t < NE / 16; t += nwaves) {
    int e = t * 16 + n;
    int src = eic[e], dst = eic[NE + e];
    const bf16x8* pu = (const bf16x8*)(u + src * 64);
    const bf16x8* pv = (const bf16x8*)(v + dst * 64);
    bf16x8 ua = pu[q], ub = pu[4 + q], va = pv[q], vb = pv[4 + q];
    f32x16 a1k;
#pragma unroll
    for (int j = 0; j < 8; ++j) {
      a1k[j] = fmaxf((float)ua[j] + (float)va[j] + bk[j], 0.f);
      a1k[8 + j] = fmaxf((float)ub[j] + (float)vb[j] + bk[8 + j], 0.f);
    }
    f32x16 z = a1k * s1k + t1k;
    bf16x8 g0h, g0l, g1h, g1l;
#pragma unroll
    for (int j = 0; j < 8; ++j) {
      float z0 = z[j], z1 = z[8 + j];
      bf16_t h0 = (bf16_t)z0, h1 = (bf16_t)z1;
      g0h[j] = h0; g0l[j] = (bf16_t)(z0 - (float)h0);
      g1h[j] = h1; g1l[j] = (bf16_t)(z1 - (float)h1);
    }
    f32x4 c0 = {0.f, 0.f, 0.f, 0.f}, c1 = {0.f, 0.f, 0.f, 0.f};
    c0 = __builtin_amdgcn_mfma_f32_16x16x32_bf16(g0h, b2h00, c0, 0, 0, 0);
    c0 = __builtin_amdgcn_mfma_f32_16x16x32_bf16(g0l, b2h00, c0, 0, 0, 0);
    c0 = __builtin_amdgcn_mfma_f32_16x16x32_bf16(g1h, b2h10, c0, 0, 0, 0);
    c0 = __builtin_amdgcn_mfma_f32_16x16x32_bf16(g1l, b2h10, c0, 0, 0, 0);
    c1 = __builtin_amdgcn_mfma_f32_16x16x32_bf16(g0h, b2h01, c1, 0, 0, 0);
    c1 = __builtin_amdgcn_mfma_f32_16x16x32_bf16(g0l, b2h01, c1, 0, 0, 0);
    c1 = __builtin_amdgcn_mfma_f32_16x16x32_bf16(g1h, b2h11, c1, 0, 0, 0);
    c1 = __builtin_amdgcn_mfma_f32_16x16x32_bf16(g1l, b2h11, c1, 0, 0, 0);
#pragma unroll
    for (int r = 0; r < 4; ++r) {
      float v0 = fmaxf(c0[r] + bias20, 0.f);
      float v1 = fmaxf(c1[r] + bias21, 0.f);
      if (STORE) {
        a2s[(size_t)(t * 16 + q * 4 + r) * 32 + n] = (bf16_t)v0;
        a2s[(size_t)(t * 16 + q * 4 + r) * 32 + 16 + n] = (bf16_t)v1;
      }
      accs0 += v0; accq0 += v0 * v0;
      accs1 += v1; accq1 += v1 * v1;
    }
  }
  {
    float s = accs0, qq = accq0;
    s += __shfl_xor(s, 16); s += __shfl_xor(s, 32);
    qq += __shfl_xor(qq, 16); qq += __shfl_xor(qq, 32);
    if (lane < 16) {
      unsafeAtomicAdd(&sum2[lane], s);
      unsafeAtomicAdd(&sq2[lane], qq);
    }
    s = accs1; qq = accq1;
    s += __shfl_xor(s, 16); s += __shfl_xor(s, 32);
    qq += __shfl_xor(qq, 16); qq += __shfl_xor(qq, 32);
    if (lane < 16) {
      unsafeAtomicAdd(&sum2[16 + lane], s);
      unsafeAtomicAdd(&sq2[16 + lane], qq);
    }
  }
}

// ============ pass 3 tier B: stream stored a2 (original order) -> out ============
template <typename OT>
__global__ __launch_bounds__(256) void k_out_stream(const bf16_t* __restrict__ a2s,
                                                    const float* __restrict__ s2,
                                                    const float* __restrict__ t2,
                                                    const float* __restrict__ Wm3f,
                                                    const float* __restrict__ bm3f,
                                                    OT* __restrict__ out,
                                                    const int* __restrict__ flags) {
  if (flags[0] != (int)(sizeof(OT) == 2)) return;
  int lane = threadIdx.x & 63;
  int wave = blockIdx.x * 4 + (threadIdx.x >> 6);
  int nwaves = gridDim.x * 4;
  int half = lane & 1;
  int sub = lane >> 1;  // 0..31
  f32x16 s2c, t2c, w0, w1;
#pragma unroll
  for (int i = 0; i < 16; ++i) {
    int c = half * 16 + i;
    s2c[i] = s2[c]; t2c[i] = t2[c];
    w0[i] = Wm3f[c * 2 + 0]; w1[i] = Wm3f[c * 2 + 1];
  }
  float bb0 = bm3f[0], bb1 = bm3f[1];
  const int ntiles = NE / 32;
#pragma unroll 2
  for (int t = wave; t < ntiles; t += nwaves) {
    int e = t * 32 + sub;
    const bf16x8* pa = (const bf16x8*)(a2s + (size_t)e * 32 + half * 16);
    bf16x8 v0 = pa[0], v1 = pa[1];
    float o0 = 0.f, o1 = 0.f;
#pragma unroll
    for (int i = 0; i < 8; ++i) {
      float z = (float)v0[i] * s2c[i] + t2c[i];
      o0 += z * w0[i]; o1 += z * w1[i];
      float z2 = (float)v1[i] * s2c[8 + i] + t2c[8 + i];
      o0 += z2 * w0[8 + i]; o1 += z2 * w1[8 + i];
    }
    o0 += __shfl_xor(o0, 1);
    o1 += __shfl_xor(o1, 1);
    if (half == 0) {
      o0 += bb0; o1 += bb1;
      if (sizeof(OT) == 2) {
        bf16_t p[2] = {(bf16_t)o0, (bf16_t)o1};
        unsigned pw;
        memcpy(&pw, p, 4);
        ((unsigned*)out)[e] = pw;
      } else {
        f32x2 pw = {o0, o1};
        ((f32x2*)out)[e] = pw;
      }
    }
  }
}

// ============ pass 3 tier C: recompute a2 and reduce -> out ============
template <typename OT>
__global__ __launch_bounds__(256) void k_out_recomp(const int* __restrict__ eic,
                                                    const bf16_t* __restrict__ u,
                                                    const bf16_t* __restrict__ v,
                                                    const float* __restrict__ bm1f,
                                                    const float* __restrict__ s1, const float* __restrict__ t1,
                                                    const float* __restrict__ Wm2f,
                                                    const float* __restrict__ bm2f,
                                                    const float* __restrict__ s2, const float* __restrict__ t2,
                                                    const float* __restrict__ Wm3f,
                                                    const float* __restrict__ bm3f,
                                                    OT* __restrict__ out,
                                                    const int* __restrict__ flags) {
  if (flags[0] != (int)(sizeof(OT) == 2)) return;
  int lane = threadIdx.x & 63;
  int wave = blockIdx.x * 4 + (threadIdx.x >> 6);
  int nwaves = gridDim.x * 4;
  int n = lane & 15, q = lane >> 4;
  f32x16 bk, s1k, t1k;
#pragma unroll
  for (int j = 0; j < 8; ++j) {
    bk[j] = bm1f[q * 8 + j];       bk[8 + j] = bm1f[32 + q * 8 + j];
    s1k[j] = s1[q * 8 + j];        s1k[8 + j] = s1[32 + q * 8 + j];
    t1k[j] = t1[q * 8 + j];        t1k[8 + j] = t1[32 + q * 8 + j];
  }
  bf16x8 b2h00, b2h01, b2h10, b2h11;
#pragma unroll
  for (int j = 0; j < 8; ++j) {
    b2h00[j] = (bf16_t)Wm2f[(q * 8 + j) * 32 + 0 * 16 + n];
    b2h01[j] = (bf16_t)Wm2f[(q * 8 + j) * 32 + 1 * 16 + n];
    b2h10[j] = (bf16_t)Wm2f[(32 + q * 8 + j) * 32 + 0 * 16 + n];
    b2h11[j] = (bf16_t)Wm2f[(32 + q * 8 + j) * 32 + 1 * 16 + n];
  }
  float bias20 = bm2f[n], bias21 = bm2f[16 + n];
  float s2c0 = s2[n], t2c0 = t2[n], s2c1 = s2[16 + n], t2c1 = t2[16 + n];
  float w3a0 = Wm3f[n * 2 + 0], w3a1 = Wm3f[n * 2 + 1];
  float w3b0 = Wm3f[(16 + n) * 2 + 0], w3b1 = Wm3f[(16 + n) * 2 + 1];
  float bb0 = bm3f[0], bb1 = bm3f[1];

  for (int t = wave; t < NE / 16; t += nwaves) {
    int e = t * 16 + n;
    int src = eic[e], dst = eic[NE + e];
    const bf16x8* pu = (const bf16x8*)(u + src * 64);
    const bf16x8* pv = (const bf16x8*)(v + dst * 64);
    bf16x8 ua = pu[q], ub = pu[4 + q], va = pv[q], vb = pv[4 + q];
    f32x16 a1k;
#pragma unroll
    for (int j = 0; j < 8; ++j) {
      a1k[j] = fmaxf((float)ua[j] + (float)va[j] + bk[j], 0.f);
      a1k[8 + j] = fmaxf((float)ub[j] + (float)vb[j] + bk[8 + j], 0.f);
    }
    f32x16 z = a1k * s1k + t1k;
    bf16x8 g0h, g0l, g1h, g1l;
#pragma unroll
    for (int j = 0; j < 8; ++j) {
      float z0 = z[j], z1 = z[8 + j];
      bf16_t h0 = (bf16_t)z0, h1 = (bf16_t)z1;
      g0h[j] = h0; g0l[j] = (bf16_t)(z0 - (float)h0);
      g1h[j] = h1; g1l[j] = (bf16_t)(z1 - (float)h1);
    }
    f32x4 c0 = {0.f, 0.f, 0.f, 0.f}, c1 = {0.f, 0.f, 0.f, 0.f};
    c0 = __builtin_amdgcn_mfma_f32_16x16x32_bf16(g0h, b2h00, c0, 0, 0, 0);
    c0 = __builtin_amdgcn_mfma_f32_16x16x32_bf16(g0l, b2h00, c0, 0, 0, 0);
    c0 = __builtin_amdgcn_mfma_f32_16x16x32_bf16(g1h, b2h10, c0, 0, 0, 0);
    c0 = __builtin_amdgcn_mfma_f32_16x16x32_bf16(g1l, b2h10, c0, 0, 0, 0);
    c1 = __builtin_amdgcn_mfma_f32_16x16x32_bf16(g0h, b2h01, c1, 0, 0, 0);
    c1 = __builtin_amdgcn_mfma_f32_16x16x32_bf16(g0l, b2h01, c1, 0, 0, 0);
    c1 = __builtin_amdgcn_mfma_f32_16x16x32_bf16(g1h, b2h11, c1, 0, 0, 0);
    c1 = __builtin_amdgcn_mfma_f32_16x16x32_bf16(g1l, b2h11, c1, 0, 0, 0);
#pragma unroll
    for (int r = 0; r < 4; ++r) {
      float z0 = fmaxf(c0[r] + bias20, 0.f) * s2c0 + t2c0;
      float z1 = fmaxf(c1[r] + bias21, 0.f) * s2c1 + t2c1;
      float o0 = z0 * w3a0 + z1 * w3b0;
      float o1 = z0 * w3a1 + z1 * w3b1;
      o0 += __shfl_xor(o0, 1); o0 += __shfl_xor(o0, 2);
      o0 += __shfl_xor(o0, 4); o0 += __shfl_xor(o0, 8);
      o1 += __shfl_xor(o1, 1); o1 += __shfl_xor(o1, 2);
      o1 += __shfl_xor(o1, 4); o1 += __shfl_xor(o1, 8);
      if (n == 0) {
        int eo = t * 16 + q * 4 + r;
        o0 += bb0; o1 += bb1;
        if (sizeof(OT) == 2) {
          bf16_t p[2] = {(bf16_t)o0, (bf16_t)o1};
          unsigned pw;
          memcpy(&pw, p, 4);
          ((unsigned*)out)[eo] = pw;
        } else {
          f32x2 pw = {o0, o1};
          ((f32x2*)out)[eo] = pw;
        }
      }
    }
  }
}

// ---------------- host ----------------
extern "C" void kernel_launch(void* const* d_in, const int* in_sizes, int n_in,
                              void* d_out, int out_size, void* d_ws, size_t ws_size,
                              hipStream_t stream) {
  (void)n_in; (void)in_sizes; (void)out_size;

  char* ws = (char*)d_ws;
  size_t off = 0;
  auto alloc = [&](size_t bytes) {
    size_t r = off;
    off = (off + bytes + 255) & ~(size_t)255;
    return r;
  };
  float* dinv  = (float*)(ws + alloc((size_t)NN * 4));
  float* hs    = (float*)(ws + alloc((size_t)NN * HID * 4));
  float* agg   = (float*)(ws + alloc((size_t)NN * HID * 4));
  int*   eic   = (int*)(ws + alloc((size_t)2 * NE * 4));
  float* stats = (float*)(ws + alloc(192 * 4));
  float* sum1 = stats, *sq1 = stats + 64, *sum2 = stats + 128, *sq2 = stats + 160;
  int*   flags = (int*)(ws + alloc(256));
  float* s1arr = (float*)(ws + alloc(64 * 4));
  float* t1arr = (float*)(ws + alloc(64 * 4));
  float* s2arr = (float*)(ws + alloc(32 * 4));
  float* t2arr = (float*)(ws + alloc(32 * 4));
  // dst-CSR (GCN gather)
  int* cnt     = (int*)(ws + alloc((size_t)NN * 4));
  int* rowptr  = (int*)(ws + alloc((size_t)NN * 4));
  int* cursor  = (int*)(ws + alloc((size_t)NN * 4));
  int* bsum    = (int*)(ws + alloc(512 * 4));
  int* btop    = (int*)(ws + alloc(512 * 4));
  int* csr_src = (int*)(ws + alloc((size_t)NE * 4));
  // node-level MLP factors
  bf16_t* u    = (bf16_t*)(ws + alloc((size_t)NN * HID * 2));
  bf16_t* v    = (bf16_t*)(ws + alloc((size_t)NN * HID * 2));

  // canonical f32 input block
  static const int flens[17] = {NN * 3, 3 * 64, 64, 64 * 64, 64, 64 * 64, 64,
                                128 * 64, 64, 64, 64, 64 * 32, 32, 32, 32, 32 * 2, 2};
  FPtrs fp;
  int total_f = 0;
  {
    int fi = 0;
    for (int i = 0; i < 18; ++i) {
      if (i == 1) continue;
      fp.p[fi] = d_in[i];
      fp.len[fi] = flens[fi];
      fp.ofs[fi] = total_f;
      total_f += flens[fi];
      ++fi;
    }
  }
  float* canon = (float*)(ws + alloc((size_t)total_f * 4));
  size_t a2_off = alloc((size_t)NE * 32 * 2);
  bf16_t* a2s = (bf16_t*)(ws + a2_off);
  bool tierB = (a2_off + (size_t)NE * 32 * 2) <= ws_size;

  const float* xf   = canon + fp.ofs[0];
  const float* W1f  = canon + fp.ofs[1];
  const float* b1f  = canon + fp.ofs[2];
  const float* W2f  = canon + fp.ofs[3];
  const float* b2f  = canon + fp.ofs[4];
  const float* W3f  = canon + fp.ofs[5];
  const float* b3f  = canon + fp.ofs[6];
  const float* Wm1f = canon + fp.ofs[7];
  const float* bm1f = canon + fp.ofs[8];
  const float* g1f  = canon + fp.ofs[9];
  const float* be1f = canon + fp.ofs[10];
  const float* Wm2f = canon + fp.ofs[11];
  const float* bm2f = canon + fp.ofs[12];
  const float* g2f  = canon + fp.ofs[13];
  const float* be2f = canon + fp.ofs[14];
  const float* Wm3f = canon + fp.ofs[15];
  const float* bm3f = canon + fp.ofs[16];

  const int nh = NN * HID;
  const int nscanb = (NN + 255) / 256;  // 391

  // 0) detect dtypes, canonicalize
  k_detect<<<1, 64, 0, stream>>>((const unsigned*)d_in[0], (const int*)d_in[1], flags);
  k_cvt_idx<int><<<1600, 256, 0, stream>>>((const int*)d_in[1], eic, flags);
  k_cvt_idx<long long><<<1600, 256, 0, stream>>>((const long long*)d_in[1], eic, flags);
  k_cvt_f<float><<<640, 256, 0, stream>>>(fp, canon, flags, total_f);
  k_cvt_f<bf16_t><<<640, 256, 0, stream>>>(fp, canon, flags, total_f);

  // 1) CSR build + dinv + stats zero
  k_zero4<<<128, 256, 0, stream>>>((f32x4*)cnt, NN / 4);
  k_zero4<<<1, 64, 0, stream>>>((f32x4*)stats, 48);
  k_count<<<1600, 256, 0, stream>>>(eic + NE, cnt);
  k_dinv<<<(NN + 255) / 256, 256, 0, stream>>>(cnt, dinv);
  k_scan1<<<nscanb, 256, 0, stream>>>(cnt, rowptr, bsum, NN);
  k_scan2<<<1, 512, 0, stream>>>(bsum, btop, nscanb);
  k_scan3<<<nscanb, 256, 0, stream>>>(rowptr, btop, cursor, NN);
  k_fill<<<1600, 256, 0, stream>>>(eic, cursor, csr_src);

  // ---- GCN layer 1 ----
  k_xw1<<<(nh + 255) / 256, 256, 0, stream>>>(xf, W1f, dinv, hs);
  k_gather<true><<<2048, 256, 0, stream>>>(rowptr, cnt, csr_src, hs, dinv, b1f, agg);

  // ---- GCN layer 2 ----
  k_hw<<<4096, 256, 0, stream>>>(agg, W2f, dinv, hs);
  k_gather<true><<<2048, 256, 0, stream>>>(rowptr, cnt, csr_src, hs, dinv, b2f, agg);

  // ---- GCN layer 3 (h3 in f32, no relu) ----
  k_hw<<<4096, 256, 0, stream>>>(agg, W3f, dinv, hs);
  k_gather<false><<<2048, 256, 0, stream>>>(rowptr, cnt, csr_src, hs, dinv, b3f, agg);

  // ---- node-level factorization of MLP layer 1 ----
  k_uv<<<4096, 256, 0, stream>>>(agg, Wm1f, u, v);

  // ---- edge MLP ----
  k_e1<<<2048, 256, 0, stream>>>(eic, u, v, bm1f, sum1, sq1);
  k_bnconst<<<1, 64, 0, stream>>>(sum1, sq1, g1f, be1f, s1arr, t1arr, 64);
  if (tierB) {
    k_e2<true><<<2048, 256, 0, stream>>>(eic, u, v, bm1f, s1arr, t1arr, Wm2f, bm2f, a2s,
                                         sum2, sq2);
    k_bnconst<<<1, 64, 0, stream>>>(sum2, sq2, g2f, be2f, s2arr, t2arr, 32);
    k_out_stream<float><<<2048, 256, 0, stream>>>(a2s, s2arr, t2arr, Wm3f, bm3f,
                                                  (float*)d_out, flags);
    k_out_stream<bf16_t><<<2048, 256, 0, stream>>>(a2s, s2arr, t2arr, Wm3f, bm3f,
                                                   (bf16_t*)d_out, flags);
  } else {
    k_e2<false><<<2048, 256, 0, stream>>>(eic, u, v, bm1f, s1arr, t1arr, Wm2f, bm2f, a2s,
                                          sum2, sq2);
    k_bnconst<<<1, 64, 0, stream>>>(sum2, sq2, g2f, be2f, s2arr, t2arr, 32);
    k_out_recomp<float><<<2048, 256, 0, stream>>>(eic, u, v, bm1f, s1arr, t1arr, Wm2f,
                                                  bm2f, s2arr, t2arr, Wm3f, bm3f,
                                                  (float*)d_out, flags);
    k_out_recomp<bf16_t><<<2048, 256, 0, stream>>>(eic, u, v, bm1f, s1arr, t1arr, Wm2f,
                                                   bm2f, s2arr, t2arr, Wm3f, bm3f,
                                                   (bf16_t*)d_out, flags);
  }
}

// Round 10
// 926.170 us; speedup vs baseline: 2.7827x; 2.7827x over previous
//
#include <hip/hip_runtime.h>
#include <hip/hip_bf16.h>
#include <cstdint>
#include <cstring>

#define NN 100000
#define NE 1600000
#define HID 64
#define EPS 1e-5f

typedef __bf16 bf16_t;
typedef __attribute__((ext_vector_type(8))) __bf16 bf16x8;
typedef __attribute__((ext_vector_type(4))) float f32x4;
typedef __attribute__((ext_vector_type(2))) float f32x2;
typedef __attribute__((ext_vector_type(16))) float f32x16;

#define LDS_FENCE() asm volatile("s_waitcnt lgkmcnt(0)" ::: "memory")

// ---------------- dtype detectors ----------------
__global__ void k_detect(const unsigned* __restrict__ xw, const int* __restrict__ eiw,
                         int* __restrict__ flags) {
  int lane = threadIdx.x;  // 64
  unsigned u = xw[lane];
  unsigned lo = u & 0xFFFFu;
  unsigned e = (lo >> 7) & 0xFFu;
  bool bf_ok = (lo == 0u) || (e >= 0x50u && e <= 0x8Fu);
  unsigned long long b1 = __ballot(bf_ok);
  int v = eiw[2 * lane + 1];
  unsigned long long b2 = __ballot(v == 0);
  if (lane == 0) {
    flags[0] = (b1 == ~0ull) ? 1 : 0;
    flags[1] = (b2 == ~0ull) ? 1 : 0;
  }
}

// ---------------- input canonicalization ----------------
struct FPtrs {
  const void* p[17];
  int len[17];
  int ofs[17];
};

template <typename FT>
__global__ void k_cvt_f(FPtrs fp, float* __restrict__ canon, const int* __restrict__ flags,
                        int total) {
  if (flags[0] != (int)(sizeof(FT) == 2)) return;
  int i = blockIdx.x * blockDim.x + threadIdx.x;
  int stride = gridDim.x * blockDim.x;
  for (int t = i; t < total; t += stride) {
    int seg = 0;
    while (seg < 16 && t >= fp.ofs[seg] + fp.len[seg]) ++seg;
    canon[t] = (float)((const FT*)fp.p[seg])[t - fp.ofs[seg]];
  }
}

template <typename IT>
__global__ void k_cvt_idx(const IT* __restrict__ ei, int* __restrict__ eic,
                          const int* __restrict__ flags) {
  if (flags[1] != (int)(sizeof(IT) == 8)) return;
  int i = blockIdx.x * blockDim.x + threadIdx.x;
  int stride = gridDim.x * blockDim.x;
  for (int t = i; t < 2 * NE; t += stride) eic[t] = (int)ei[t];
}

// ---------------- utility: zero fill ----------------
__global__ void k_zero4(f32x4* __restrict__ p, int n4) {
  int i = blockIdx.x * blockDim.x + threadIdx.x;
  int stride = gridDim.x * blockDim.x;
  f32x4 z = {0.f, 0.f, 0.f, 0.f};
  for (int t = i; t < n4; t += stride) p[t] = z;
}

// ---------------- CSR build (dst-major, for GCN gather) ----------------
__global__ void k_count(const int* __restrict__ col, int* __restrict__ cnt) {
  int i = blockIdx.x * blockDim.x + threadIdx.x;
  int stride = gridDim.x * blockDim.x;
  for (int e = i; e < NE; e += stride) atomicAdd(&cnt[col[e]], 1);
}

__global__ void k_dinv(const int* __restrict__ cnt, float* __restrict__ d) {
  int n = blockIdx.x * blockDim.x + threadIdx.x;
  if (n < NN) d[n] = rsqrtf((float)cnt[n] + 1.0f);  // self-loop
}

__global__ void k_scan1(const int* __restrict__ cnt, int* __restrict__ rowptr,
                        int* __restrict__ bsum, int nvals) {
  __shared__ int tmp[256];
  int gid = blockIdx.x * 256 + threadIdx.x;
  int v = (gid < nvals) ? cnt[gid] : 0;
  tmp[threadIdx.x] = v;
  __syncthreads();
  for (int s = 1; s < 256; s <<= 1) {
    int add = (threadIdx.x >= s) ? tmp[threadIdx.x - s] : 0;
    __syncthreads();
    tmp[threadIdx.x] += add;
    __syncthreads();
  }
  if (gid < nvals) rowptr[gid] = tmp[threadIdx.x] - v;
  if (threadIdx.x == 255) bsum[blockIdx.x] = tmp[255];
}

__global__ void k_scan2(int* __restrict__ bsum, int* __restrict__ btop, int nblocks) {
  __shared__ int tmp[512];
  int v = (threadIdx.x < nblocks) ? bsum[threadIdx.x] : 0;
  tmp[threadIdx.x] = v;
  __syncthreads();
  for (int s = 1; s < 512; s <<= 1) {
    int add = (threadIdx.x >= s) ? tmp[threadIdx.x - s] : 0;
    __syncthreads();
    tmp[threadIdx.x] += add;
    __syncthreads();
  }
  if (threadIdx.x < nblocks) btop[threadIdx.x] = tmp[threadIdx.x] - v;
}

__global__ void k_scan3(int* __restrict__ rowptr, const int* __restrict__ btop,
                        int* __restrict__ cursor, int nvals) {
  int gid = blockIdx.x * 256 + threadIdx.x;
  if (gid < nvals) {
    int v = rowptr[gid] + btop[blockIdx.x];
    rowptr[gid] = v;
    cursor[gid] = v;
  }
}

__global__ void k_fill(const int* __restrict__ eic, int* __restrict__ cursor,
                       int* __restrict__ csr_src) {
  int i = blockIdx.x * blockDim.x + threadIdx.x;
  int stride = gridDim.x * blockDim.x;
  for (int e = i; e < NE; e += stride) {
    int src = eic[e], dst = eic[NE + e];
    int pos = atomicAdd(&cursor[dst], 1);
    csr_src[pos] = src;
  }
}

// ---------------- layer 1: hs = (x @ W1) * dinv ----------------
__global__ void k_xw1(const float* __restrict__ x, const float* __restrict__ W1,
                      const float* __restrict__ dinv, float* __restrict__ hs) {
  int gid = blockIdx.x * blockDim.x + threadIdx.x;
  if (gid >= NN * HID) return;
  int n = gid >> 6, j = gid & 63;
  float acc = x[n * 3 + 0] * W1[0 * 64 + j] + x[n * 3 + 1] * W1[1 * 64 + j] +
              x[n * 3 + 2] * W1[2 * 64 + j];
  hs[gid] = acc * dinv[n];
}

// ---------------- hs = (h @ W) * dinv ----------------
__global__ __launch_bounds__(256) void k_hw(const float* __restrict__ h,
                                            const float* __restrict__ W,
                                            const float* __restrict__ dinv,
                                            float* __restrict__ hs) {
  __shared__ float Wl[64 * 64];
  __shared__ float hrow[4][64];
  int tid = threadIdx.x;
  for (int i = tid; i < 64 * 64; i += 256) Wl[i] = W[i];
  __syncthreads();
  int w = tid >> 6, j = tid & 63;
  for (int nb = blockIdx.x * 4 + w; nb < NN; nb += gridDim.x * 4) {
    hrow[w][j] = h[nb * 64 + j];
    LDS_FENCE();
    float acc = 0.f;
#pragma unroll 8
    for (int k = 0; k < 64; ++k) acc += hrow[w][k] * Wl[k * 64 + j];
    hs[nb * 64 + j] = acc * dinv[nb];
  }
}

// ---------------- gather-aggregate + fused finalize ----------------
template <bool RELU>
__global__ __launch_bounds__(256) void k_gather(const int* __restrict__ rowptr,
                                                const int* __restrict__ cnt,
                                                const int* __restrict__ csr_src,
                                                const float* __restrict__ hs,
                                                const float* __restrict__ dinv,
                                                const float* __restrict__ b,
                                                float* __restrict__ outf) {
  int wid = (blockIdx.x * blockDim.x + threadIdx.x) >> 6;
  int nw = (gridDim.x * blockDim.x) >> 6;
  int j = threadIdx.x & 63;
  for (int n = wid; n < NN; n += nw) {
    int beg = rowptr[n], c = cnt[n];
    float acc = hs[n * 64 + j];  // self-loop
    int k = 0;
    for (; k + 8 <= c; k += 8) {
      int s0 = csr_src[beg + k + 0], s1 = csr_src[beg + k + 1];
      int s2 = csr_src[beg + k + 2], s3 = csr_src[beg + k + 3];
      int s4 = csr_src[beg + k + 4], s5 = csr_src[beg + k + 5];
      int s6 = csr_src[beg + k + 6], s7 = csr_src[beg + k + 7];
      float v0 = hs[s0 * 64 + j], v1 = hs[s1 * 64 + j];
      float v2 = hs[s2 * 64 + j], v3 = hs[s3 * 64 + j];
      float v4 = hs[s4 * 64 + j], v5 = hs[s5 * 64 + j];
      float v6 = hs[s6 * 64 + j], v7 = hs[s7 * 64 + j];
      acc += ((v0 + v1) + (v2 + v3)) + ((v4 + v5) + (v6 + v7));
    }
    for (; k < c; ++k) acc += hs[csr_src[beg + k] * 64 + j];
    float v = acc * dinv[n] + b[j];
    outf[n * 64 + j] = RELU ? fmaxf(v, 0.f) : v;
  }
}

// ---------------- node-level factorization: u = h3@Wm1_top, v = h3@Wm1_bot ----------------
__global__ __launch_bounds__(256) void k_uv(const float* __restrict__ h3,
                                            const float* __restrict__ Wm1f,
                                            bf16_t* __restrict__ u, bf16_t* __restrict__ v) {
  __shared__ float Wt[64 * 64];
  __shared__ float Wb[64 * 64];
  __shared__ float hrow[4][64];
  int tid = threadIdx.x;
  for (int i = tid; i < 64 * 64; i += 256) {
    Wt[i] = Wm1f[i];
    Wb[i] = Wm1f[4096 + i];
  }
  __syncthreads();
  int w = tid >> 6, j = tid & 63;
  for (int nb = blockIdx.x * 4 + w; nb < NN; nb += gridDim.x * 4) {
    hrow[w][j] = h3[nb * 64 + j];
    LDS_FENCE();
    float au = 0.f, av = 0.f;
#pragma unroll 8
    for (int k = 0; k < 64; ++k) {
      float hv = hrow[w][k];
      au += hv * Wt[k * 64 + j];
      av += hv * Wb[k * 64 + j];
    }
    u[nb * 64 + j] = (bf16_t)au;
    v[nb * 64 + j] = (bf16_t)av;
  }
}

// ============ pass 1: BN1 stats of a1 = relu(u[src]+v[dst]+bm1) ============
// Stats: butterfly in-wave -> LDS block reduction -> ONE dense atomic per block.
__global__ __launch_bounds__(256) void k_e1(const int* __restrict__ eic,
                                            const bf16_t* __restrict__ u,
                                            const bf16_t* __restrict__ v,
                                            const float* __restrict__ bm1f,
                                            float* __restrict__ sum1,
                                            float* __restrict__ sq1) {
  __shared__ float reds[16][16];
  __shared__ float redq[16][16];
  int lane = threadIdx.x & 63;
  int wv = threadIdx.x >> 6;
  int wave = blockIdx.x * 4 + wv;
  int nwaves = gridDim.x * 4;
  int n = lane & 15, q = lane >> 4;
  f32x16 bk;
#pragma unroll
  for (int j = 0; j < 8; ++j) {
    bk[j] = bm1f[q * 8 + j];
    bk[8 + j] = bm1f[32 + q * 8 + j];
  }
  f32x16 accs = {};
  f32x16 accq = {};
#pragma unroll 2
  for (int t = wave; t < NE / 16; t += nwaves) {
    int e = t * 16 + n;
    int src = eic[e], dst = eic[NE + e];
    const bf16x8* pu = (const bf16x8*)(u + src * 64);
    const bf16x8* pv = (const bf16x8*)(v + dst * 64);
    bf16x8 ua = pu[q], ub = pu[4 + q], va = pv[q], vb = pv[4 + q];
    f32x16 a1k;
#pragma unroll
    for (int j = 0; j < 8; ++j) {
      a1k[j] = fmaxf((float)ua[j] + (float)va[j] + bk[j], 0.f);
      a1k[8 + j] = fmaxf((float)ub[j] + (float)vb[j] + bk[8 + j], 0.f);
    }
    accs += a1k;
    accq += a1k * a1k;
  }
  // butterfly over n (lane bits 0-3)
#pragma unroll
  for (int j = 0; j < 16; ++j) {
    float s = accs[j], qq = accq[j];
    s += __shfl_xor(s, 1); s += __shfl_xor(s, 2);
    s += __shfl_xor(s, 4); s += __shfl_xor(s, 8);
    qq += __shfl_xor(qq, 1); qq += __shfl_xor(qq, 2);
    qq += __shfl_xor(qq, 4); qq += __shfl_xor(qq, 8);
    if (n == 0) {
      reds[wv * 4 + q][j] = s;
      redq[wv * 4 + q][j] = qq;
    }
  }
  __syncthreads();
  int tid = threadIdx.x;
  if (tid < 64) {
    // col tid: quad jq = (tid&31)>>3, elem = (tid>>5)*8 + (tid&7)
    int jq = (tid & 31) >> 3, elem = (tid >> 5) * 8 + (tid & 7);
    float s = reds[jq][elem] + reds[4 + jq][elem] + reds[8 + jq][elem] + reds[12 + jq][elem];
    float qq = redq[jq][elem] + redq[4 + jq][elem] + redq[8 + jq][elem] + redq[12 + jq][elem];
    unsafeAtomicAdd(&sum1[tid], s);
    unsafeAtomicAdd(&sq1[tid], qq);
  }
}

// ---------------- BN affine constants ----------------
__global__ void k_bnconst(const float* __restrict__ sum, const float* __restrict__ sq,
                          const float* __restrict__ g, const float* __restrict__ be,
                          float* __restrict__ sarr, float* __restrict__ tarr, int ncol) {
  int j = threadIdx.x;
  if (j >= ncol) return;
  float mu = sum[j] / (float)NE;
  float var = fmaxf(sq[j] / (float)NE - mu * mu, 0.f);
  float s = g[j] * rsqrtf(var + EPS);
  sarr[j] = s;
  tarr[j] = be[j] - mu * s;
}

// ============ pass 2: BN2 stats of a2 (+ optional store of pre-BN a2) ============
template <bool STORE>
__global__ __launch_bounds__(256) void k_e2(const int* __restrict__ eic,
                                            const bf16_t* __restrict__ u,
                                            const bf16_t* __restrict__ v,
                                            const float* __restrict__ bm1f,
                                            const float* __restrict__ s1, const float* __restrict__ t1,
                                            const float* __restrict__ Wm2f,
                                            const float* __restrict__ bm2f,
                                            bf16_t* __restrict__ a2s,
                                            float* __restrict__ sum2,
                                            float* __restrict__ sq2) {
  __shared__ float red2[4][4][16];  // [wv][{s0,q0,s1,q1}][n]
  int lane = threadIdx.x & 63;
  int wv = threadIdx.x >> 6;
  int wave = blockIdx.x * 4 + wv;
  int nwaves = gridDim.x * 4;
  int n = lane & 15, q = lane >> 4;
  f32x16 bk, s1k, t1k;
#pragma unroll
  for (int j = 0; j < 8; ++j) {
    bk[j] = bm1f[q * 8 + j];       bk[8 + j] = bm1f[32 + q * 8 + j];
    s1k[j] = s1[q * 8 + j];        s1k[8 + j] = s1[32 + q * 8 + j];
    t1k[j] = t1[q * 8 + j];        t1k[8 + j] = t1[32 + q * 8 + j];
  }
  bf16x8 b2h00, b2h01, b2h10, b2h11;
#pragma unroll
  for (int j = 0; j < 8; ++j) {
    b2h00[j] = (bf16_t)Wm2f[(q * 8 + j) * 32 + 0 * 16 + n];
    b2h01[j] = (bf16_t)Wm2f[(q * 8 + j) * 32 + 1 * 16 + n];
    b2h10[j] = (bf16_t)Wm2f[(32 + q * 8 + j) * 32 + 0 * 16 + n];
    b2h11[j] = (bf16_t)Wm2f[(32 + q * 8 + j) * 32 + 1 * 16 + n];
  }
  float bias20 = bm2f[n], bias21 = bm2f[16 + n];
  float accs0 = 0.f, accs1 = 0.f, accq0 = 0.f, accq1 = 0.f;
  for (int t = wave; t < NE / 16; t += nwaves) {
    int e = t * 16 + n;
    int src = eic[e], dst = eic[NE + e];
    const bf16x8* pu = (const bf16x8*)(u + src * 64);
    const bf16x8* pv = (const bf16x8*)(v + dst * 64);
    bf16x8 ua = pu[q], ub = pu[4 + q], va = pv[q], vb = pv[4 + q];
    f32x16 a1k;
#pragma unroll
    for (int j = 0; j < 8; ++j) {
      a1k[j] = fmaxf((float)ua[j] + (float)va[j] + bk[j], 0.f);
      a1k[8 + j] = fmaxf((float)ub[j] + (float)vb[j] + bk[8 + j], 0.f);
    }
    f32x16 z = a1k * s1k + t1k;
    bf16x8 g0h, g0l, g1h, g1l;
#pragma unroll
    for (int j = 0; j < 8; ++j) {
      float z0 = z[j], z1 = z[8 + j];
      bf16_t h0 = (bf16_t)z0, h1 = (bf16_t)z1;
      g0h[j] = h0; g0l[j] = (bf16_t)(z0 - (float)h0);
      g1h[j] = h1; g1l[j] = (bf16_t)(z1 - (float)h1);
    }
    f32x4 c0 = {0.f, 0.f, 0.f, 0.f}, c1 = {0.f, 0.f, 0.f, 0.f};
    c0 = __builtin_amdgcn_mfma_f32_16x16x32_bf16(g0h, b2h00, c0, 0, 0, 0);
    c0 = __builtin_amdgcn_mfma_f32_16x16x32_bf16(g0l, b2h00, c0, 0, 0, 0);
    c0 = __builtin_amdgcn_mfma_f32_16x16x32_bf16(g1h, b2h10, c0, 0, 0, 0);
    c0 = __builtin_amdgcn_mfma_f32_16x16x32_bf16(g1l, b2h10, c0, 0, 0, 0);
    c1 = __builtin_amdgcn_mfma_f32_16x16x32_bf16(g0h, b2h01, c1, 0, 0, 0);
    c1 = __builtin_amdgcn_mfma_f32_16x16x32_bf16(g0l, b2h01, c1, 0, 0, 0);
    c1 = __builtin_amdgcn_mfma_f32_16x16x32_bf16(g1h, b2h11, c1, 0, 0, 0);
    c1 = __builtin_amdgcn_mfma_f32_16x16x32_bf16(g1l, b2h11, c1, 0, 0, 0);
#pragma unroll
    for (int r = 0; r < 4; ++r) {
      float v0 = fmaxf(c0[r] + bias20, 0.f);
      float v1 = fmaxf(c1[r] + bias21, 0.f);
      if (STORE) {
        a2s[(size_t)(t * 16 + q * 4 + r) * 32 + n] = (bf16_t)v0;
        a2s[(size_t)(t * 16 + q * 4 + r) * 32 + 16 + n] = (bf16_t)v1;
      }
      accs0 += v0; accq0 += v0 * v0;
      accs1 += v1; accq1 += v1 * v1;
    }
  }
  // butterfly over q (lane bits 4,5), stage in LDS, one dense atomic per block
  accs0 += __shfl_xor(accs0, 16); accs0 += __shfl_xor(accs0, 32);
  accq0 += __shfl_xor(accq0, 16); accq0 += __shfl_xor(accq0, 32);
  accs1 += __shfl_xor(accs1, 16); accs1 += __shfl_xor(accs1, 32);
  accq1 += __shfl_xor(accq1, 16); accq1 += __shfl_xor(accq1, 32);
  if (lane < 16) {
    red2[wv][0][lane] = accs0;
    red2[wv][1][lane] = accq0;
    red2[wv][2][lane] = accs1;
    red2[wv][3][lane] = accq1;
  }
  __syncthreads();
  int tid = threadIdx.x;
  if (tid < 32) {
    int which = tid >> 4, nn = tid & 15;
    float s = red2[0][which * 2][nn] + red2[1][which * 2][nn] + red2[2][which * 2][nn] +
              red2[3][which * 2][nn];
    float qq = red2[0][which * 2 + 1][nn] + red2[1][which * 2 + 1][nn] +
               red2[2][which * 2 + 1][nn] + red2[3][which * 2 + 1][nn];
    unsafeAtomicAdd(&sum2[tid], s);
    unsafeAtomicAdd(&sq2[tid], qq);
  }
}

// ============ pass 3 tier B: stream stored a2 (original order) -> out ============
template <typename OT>
__global__ __launch_bounds__(256) void k_out_stream(const bf16_t* __restrict__ a2s,
                                                    const float* __restrict__ s2,
                                                    const float* __restrict__ t2,
                                                    const float* __restrict__ Wm3f,
                                                    const float* __restrict__ bm3f,
                                                    OT* __restrict__ out,
                                                    const int* __restrict__ flags) {
  if (flags[0] != (int)(sizeof(OT) == 2)) return;
  int lane = threadIdx.x & 63;
  int wave = blockIdx.x * 4 + (threadIdx.x >> 6);
  int nwaves = gridDim.x * 4;
  int half = lane & 1;
  int sub = lane >> 1;  // 0..31
  f32x16 s2c, t2c, w0, w1;
#pragma unroll
  for (int i = 0; i < 16; ++i) {
    int c = half * 16 + i;
    s2c[i] = s2[c]; t2c[i] = t2[c];
    w0[i] = Wm3f[c * 2 + 0]; w1[i] = Wm3f[c * 2 + 1];
  }
  float bb0 = bm3f[0], bb1 = bm3f[1];
  const int ntiles = NE / 32;
#pragma unroll 2
  for (int t = wave; t < ntiles; t += nwaves) {
    int e = t * 32 + sub;
    const bf16x8* pa = (const bf16x8*)(a2s + (size_t)e * 32 + half * 16);
    bf16x8 v0 = pa[0], v1 = pa[1];
    float o0 = 0.f, o1 = 0.f;
#pragma unroll
    for (int i = 0; i < 8; ++i) {
      float z = (float)v0[i] * s2c[i] + t2c[i];
      o0 += z * w0[i]; o1 += z * w1[i];
      float z2 = (float)v1[i] * s2c[8 + i] + t2c[8 + i];
      o0 += z2 * w0[8 + i]; o1 += z2 * w1[8 + i];
    }
    o0 += __shfl_xor(o0, 1);
    o1 += __shfl_xor(o1, 1);
    if (half == 0) {
      o0 += bb0; o1 += bb1;
      if (sizeof(OT) == 2) {
        bf16_t p[2] = {(bf16_t)o0, (bf16_t)o1};
        unsigned pw;
        memcpy(&pw, p, 4);
        ((unsigned*)out)[e] = pw;
      } else {
        f32x2 pw = {o0, o1};
        ((f32x2*)out)[e] = pw;
      }
    }
  }
}

// ============ pass 3 tier C: recompute a2 and reduce -> out ============
template <typename OT>
__global__ __launch_bounds__(256) void k_out_recomp(const int* __restrict__ eic,
                                                    const bf16_t* __restrict__ u,
                                                    const bf16_t* __restrict__ v,
                                                    const float* __restrict__ bm1f,
                                                    const float* __restrict__ s1, const float* __restrict__ t1,
                                                    const float* __restrict__ Wm2f,
                                                    const float* __restrict__ bm2f,
                                                    const float* __restrict__ s2, const float* __restrict__ t2,
                                                    const float* __restrict__ Wm3f,
                                                    const float* __restrict__ bm3f,
                                                    OT* __restrict__ out,
                                                    const int* __restrict__ flags) {
  if (flags[0] != (int)(sizeof(OT) == 2)) return;
  int lane = threadIdx.x & 63;
  int wave = blockIdx.x * 4 + (threadIdx.x >> 6);
  int nwaves = gridDim.x * 4;
  int n = lane & 15, q = lane >> 4;
  f32x16 bk, s1k, t1k;
#pragma unroll
  for (int j = 0; j < 8; ++j) {
    bk[j] = bm1f[q * 8 + j];       bk[8 + j] = bm1f[32 + q * 8 + j];
    s1k[j] = s1[q * 8 + j];        s1k[8 + j] = s1[32 + q * 8 + j];
    t1k[j] = t1[q * 8 + j];        t1k[8 + j] = t1[32 + q * 8 + j];
  }
  bf16x8 b2h00, b2h01, b2h10, b2h11;
#pragma unroll
  for (int j = 0; j < 8; ++j) {
    b2h00[j] = (bf16_t)Wm2f[(q * 8 + j) * 32 + 0 * 16 + n];
    b2h01[j] = (bf16_t)Wm2f[(q * 8 + j) * 32 + 1 * 16 + n];
    b2h10[j] = (bf16_t)Wm2f[(32 + q * 8 + j) * 32 + 0 * 16 + n];
    b2h11[j] = (bf16_t)Wm2f[(32 + q * 8 + j) * 32 + 1 * 16 + n];
  }
  float bias20 = bm2f[n], bias21 = bm2f[16 + n];
  float s2c0 = s2[n], t2c0 = t2[n], s2c1 = s2[16 + n], t2c1 = t2[16 + n];
  float w3a0 = Wm3f[n * 2 + 0], w3a1 = Wm3f[n * 2 + 1];
  float w3b0 = Wm3f[(16 + n) * 2 + 0], w3b1 = Wm3f[(16 + n) * 2 + 1];
  float bb0 = bm3f[0], bb1 = bm3f[1];

  for (int t = wave; t < NE / 16; t += nwaves) {
    int e = t * 16 + n;
    int src = eic[e], dst = eic[NE + e];
    const bf16x8* pu = (const bf16x8*)(u + src * 64);
    const bf16x8* pv = (const bf16x8*)(v + dst * 64);
    bf16x8 ua = pu[q], ub = pu[4 + q], va = pv[q], vb = pv[4 + q];
    f32x16 a1k;
#pragma unroll
    for (int j = 0; j < 8; ++j) {
      a1k[j] = fmaxf((float)ua[j] + (float)va[j] + bk[j], 0.f);
      a1k[8 + j] = fmaxf((float)ub[j] + (float)vb[j] + bk[8 + j], 0.f);
    }
    f32x16 z = a1k * s1k + t1k;
    bf16x8 g0h, g0l, g1h, g1l;
#pragma unroll
    for (int j = 0; j < 8; ++j) {
      float z0 = z[j], z1 = z[8 + j];
      bf16_t h0 = (bf16_t)z0, h1 = (bf16_t)z1;
      g0h[j] = h0; g0l[j] = (bf16_t)(z0 - (float)h0);
      g1h[j] = h1; g1l[j] = (bf16_t)(z1 - (float)h1);
    }
    f32x4 c0 = {0.f, 0.f, 0.f, 0.f}, c1 = {0.f, 0.f, 0.f, 0.f};
    c0 = __builtin_amdgcn_mfma_f32_16x16x32_bf16(g0h, b2h00, c0, 0, 0, 0);
    c0 = __builtin_amdgcn_mfma_f32_16x16x32_bf16(g0l, b2h00, c0, 0, 0, 0);
    c0 = __builtin_amdgcn_mfma_f32_16x16x32_bf16(g1h, b2h10, c0, 0, 0, 0);
    c0 = __builtin_amdgcn_mfma_f32_16x16x32_bf16(g1l, b2h10, c0, 0, 0, 0);
    c1 = __builtin_amdgcn_mfma_f32_16x16x32_bf16(g0h, b2h01, c1, 0, 0, 0);
    c1 = __builtin_amdgcn_mfma_f32_16x16x32_bf16(g0l, b2h01, c1, 0, 0, 0);
    c1 = __builtin_amdgcn_mfma_f32_16x16x32_bf16(g1h, b2h11, c1, 0, 0, 0);
    c1 = __builtin_amdgcn_mfma_f32_16x16x32_bf16(g1l, b2h11, c1, 0, 0, 0);
#pragma unroll
    for (int r = 0; r < 4; ++r) {
      float z0 = fmaxf(c0[r] + bias20, 0.f) * s2c0 + t2c0;
      float z1 = fmaxf(c1[r] + bias21, 0.f) * s2c1 + t2c1;
      float o0 = z0 * w3a0 + z1 * w3b0;
      float o1 = z0 * w3a1 + z1 * w3b1;
      o0 += __shfl_xor(o0, 1); o0 += __shfl_xor(o0, 2);
      o0 += __shfl_xor(o0, 4); o0 += __shfl_xor(o0, 8);
      o1 += __shfl_xor(o1, 1); o1 += __shfl_xor(o1, 2);
      o1 += __shfl_xor(o1, 4); o1 += __shfl_xor(o1, 8);
      if (n == 0) {
        int eo = t * 16 + q * 4 + r;
        o0 += bb0; o1 += bb1;
        if (sizeof(OT) == 2) {
          bf16_t p[2] = {(bf16_t)o0, (bf16_t)o1};
          unsigned pw;
          memcpy(&pw, p, 4);
          ((unsigned*)out)[eo] = pw;
        } else {
          f32x2 pw = {o0, o1};
          ((f32x2*)out)[eo] = pw;
        }
      }
    }
  }
}

// ---------------- host ----------------
extern "C" void kernel_launch(void* const* d_in, const int* in_sizes, int n_in,
                              void* d_out, int out_size, void* d_ws, size_t ws_size,
                              hipStream_t stream) {
  (void)n_in; (void)in_sizes; (void)out_size;

  char* ws = (char*)d_ws;
  size_t off = 0;
  auto alloc = [&](size_t bytes) {
    size_t r = off;
    off = (off + bytes + 255) & ~(size_t)255;
    return r;
  };
  float* dinv  = (float*)(ws + alloc((size_t)NN * 4));
  float* hs    = (float*)(ws + alloc((size_t)NN * HID * 4));
  float* agg   = (float*)(ws + alloc((size_t)NN * HID * 4));
  int*   eic   = (int*)(ws + alloc((size_t)2 * NE * 4));
  float* stats = (float*)(ws + alloc(192 * 4));
  float* sum1 = stats, *sq1 = stats + 64, *sum2 = stats + 128, *sq2 = stats + 160;
  int*   flags = (int*)(ws + alloc(256));
  float* s1arr = (float*)(ws + alloc(64 * 4));
  float* t1arr = (float*)(ws + alloc(64 * 4));
  float* s2arr = (float*)(ws + alloc(32 * 4));
  float* t2arr = (float*)(ws + alloc(32 * 4));
  // dst-CSR (GCN gather)
  int* cnt     = (int*)(ws + alloc((size_t)NN * 4));
  int* rowptr  = (int*)(ws + alloc((size_t)NN * 4));
  int* cursor  = (int*)(ws + alloc((size_t)NN * 4));
  int* bsum    = (int*)(ws + alloc(512 * 4));
  int* btop    = (int*)(ws + alloc(512 * 4));
  int* csr_src = (int*)(ws + alloc((size_t)NE * 4));
  // node-level MLP factors
  bf16_t* u    = (bf16_t*)(ws + alloc((size_t)NN * HID * 2));
  bf16_t* v    = (bf16_t*)(ws + alloc((size_t)NN * HID * 2));

  // canonical f32 input block
  static const int flens[17] = {NN * 3, 3 * 64, 64, 64 * 64, 64, 64 * 64, 64,
                                128 * 64, 64, 64, 64, 64 * 32, 32, 32, 32, 32 * 2, 2};
  FPtrs fp;
  int total_f = 0;
  {
    int fi = 0;
    for (int i = 0; i < 18; ++i) {
      if (i == 1) continue;
      fp.p[fi] = d_in[i];
      fp.len[fi] = flens[fi];
      fp.ofs[fi] = total_f;
      total_f += flens[fi];
      ++fi;
    }
  }
  float* canon = (float*)(ws + alloc((size_t)total_f * 4));
  size_t a2_off = alloc((size_t)NE * 32 * 2);
  bf16_t* a2s = (bf16_t*)(ws + a2_off);
  bool tierB = (a2_off + (size_t)NE * 32 * 2) <= ws_size;

  const float* xf   = canon + fp.ofs[0];
  const float* W1f  = canon + fp.ofs[1];
  const float* b1f  = canon + fp.ofs[2];
  const float* W2f  = canon + fp.ofs[3];
  const float* b2f  = canon + fp.ofs[4];
  const float* W3f  = canon + fp.ofs[5];
  const float* b3f  = canon + fp.ofs[6];
  const float* Wm1f = canon + fp.ofs[7];
  const float* bm1f = canon + fp.ofs[8];
  const float* g1f  = canon + fp.ofs[9];
  const float* be1f = canon + fp.ofs[10];
  const float* Wm2f = canon + fp.ofs[11];
  const float* bm2f = canon + fp.ofs[12];
  const float* g2f  = canon + fp.ofs[13];
  const float* be2f = canon + fp.ofs[14];
  const float* Wm3f = canon + fp.ofs[15];
  const float* bm3f = canon + fp.ofs[16];

  const int nh = NN * HID;
  const int nscanb = (NN + 255) / 256;  // 391

  // 0) detect dtypes, canonicalize
  k_detect<<<1, 64, 0, stream>>>((const unsigned*)d_in[0], (const int*)d_in[1], flags);
  k_cvt_idx<int><<<1600, 256, 0, stream>>>((const int*)d_in[1], eic, flags);
  k_cvt_idx<long long><<<1600, 256, 0, stream>>>((const long long*)d_in[1], eic, flags);
  k_cvt_f<float><<<640, 256, 0, stream>>>(fp, canon, flags, total_f);
  k_cvt_f<bf16_t><<<640, 256, 0, stream>>>(fp, canon, flags, total_f);

  // 1) CSR build + dinv + stats zero
  k_zero4<<<128, 256, 0, stream>>>((f32x4*)cnt, NN / 4);
  k_zero4<<<1, 64, 0, stream>>>((f32x4*)stats, 48);
  k_count<<<1600, 256, 0, stream>>>(eic + NE, cnt);
  k_dinv<<<(NN + 255) / 256, 256, 0, stream>>>(cnt, dinv);
  k_scan1<<<nscanb, 256, 0, stream>>>(cnt, rowptr, bsum, NN);
  k_scan2<<<1, 512, 0, stream>>>(bsum, btop, nscanb);
  k_scan3<<<nscanb, 256, 0, stream>>>(rowptr, btop, cursor, NN);
  k_fill<<<1600, 256, 0, stream>>>(eic, cursor, csr_src);

  // ---- GCN layer 1 ----
  k_xw1<<<(nh + 255) / 256, 256, 0, stream>>>(xf, W1f, dinv, hs);
  k_gather<true><<<2048, 256, 0, stream>>>(rowptr, cnt, csr_src, hs, dinv, b1f, agg);

  // ---- GCN layer 2 ----
  k_hw<<<4096, 256, 0, stream>>>(agg, W2f, dinv, hs);
  k_gather<true><<<2048, 256, 0, stream>>>(rowptr, cnt, csr_src, hs, dinv, b2f, agg);

  // ---- GCN layer 3 (h3 in f32, no relu) ----
  k_hw<<<4096, 256, 0, stream>>>(agg, W3f, dinv, hs);
  k_gather<false><<<2048, 256, 0, stream>>>(rowptr, cnt, csr_src, hs, dinv, b3f, agg);

  // ---- node-level factorization of MLP layer 1 ----
  k_uv<<<4096, 256, 0, stream>>>(agg, Wm1f, u, v);

  // ---- edge MLP ----
  k_e1<<<2048, 256, 0, stream>>>(eic, u, v, bm1f, sum1, sq1);
  k_bnconst<<<1, 64, 0, stream>>>(sum1, sq1, g1f, be1f, s1arr, t1arr, 64);
  if (tierB) {
    k_e2<true><<<2048, 256, 0, stream>>>(eic, u, v, bm1f, s1arr, t1arr, Wm2f, bm2f, a2s,
                                         sum2, sq2);
    k_bnconst<<<1, 64, 0, stream>>>(sum2, sq2, g2f, be2f, s2arr, t2arr, 32);
    k_out_stream<float><<<2048, 256, 0, stream>>>(a2s, s2arr, t2arr, Wm3f, bm3f,
                                                  (float*)d_out, flags);
    k_out_stream<bf16_t><<<2048, 256, 0, stream>>>(a2s, s2arr, t2arr, Wm3f, bm3f,
                                                   (bf16_t*)d_out, flags);
  } else {
    k_e2<false><<<2048, 256, 0, stream>>>(eic, u, v, bm1f, s1arr, t1arr, Wm2f, bm2f, a2s,
                                          sum2, sq2);
    k_bnconst<<<1, 64, 0, stream>>>(sum2, sq2, g2f, be2f, s2arr, t2arr, 32);
    k_out_recomp<float><<<2048, 256, 0, stream>>>(eic, u, v, bm1f, s1arr, t1arr, Wm2f,
                                                  bm2f, s2arr, t2arr, Wm3f, bm3f,
                                                  (float*)d_out, flags);
    k_out_recomp<bf16_t><<<2048, 256, 0, stream>>>(eic, u, v, bm1f, s1arr, t1arr, Wm2f,
                                                   bm2f, s2arr, t2arr, Wm3f, bm3f,
                                                   (bf16_t*)d_out, flags);
  }
}

// Round 11
// 832.243 us; speedup vs baseline: 3.0968x; 1.1129x over previous
//
#include <hip/hip_runtime.h>
#include <hip/hip_bf16.h>
#include <cstdint>
#include <cstring>

#define NN 100000
#define NE 1600000
#define HID 64
#define EPS 1e-5f

typedef __bf16 bf16_t;
typedef __attribute__((ext_vector_type(8))) __bf16 bf16x8;
typedef __attribute__((ext_vector_type(4))) float f32x4;
typedef __attribute__((ext_vector_type(2))) float f32x2;
typedef __attribute__((ext_vector_type(16))) float f32x16;

#define LDS_FENCE() asm volatile("s_waitcnt lgkmcnt(0)" ::: "memory")

// ---------------- dtype detectors ----------------
__global__ void k_detect(const unsigned* __restrict__ xw, const int* __restrict__ eiw,
                         int* __restrict__ flags) {
  int lane = threadIdx.x;  // 64
  unsigned u = xw[lane];
  unsigned lo = u & 0xFFFFu;
  unsigned e = (lo >> 7) & 0xFFu;
  bool bf_ok = (lo == 0u) || (e >= 0x50u && e <= 0x8Fu);
  unsigned long long b1 = __ballot(bf_ok);
  int v = eiw[2 * lane + 1];
  unsigned long long b2 = __ballot(v == 0);
  if (lane == 0) {
    flags[0] = (b1 == ~0ull) ? 1 : 0;
    flags[1] = (b2 == ~0ull) ? 1 : 0;
  }
}

// ---------------- input canonicalization ----------------
struct FPtrs {
  const void* p[17];
  int len[17];
  int ofs[17];
};

template <typename FT>
__global__ void k_cvt_f(FPtrs fp, float* __restrict__ canon, const int* __restrict__ flags,
                        int total) {
  if (flags[0] != (int)(sizeof(FT) == 2)) return;
  int i = blockIdx.x * blockDim.x + threadIdx.x;
  int stride = gridDim.x * blockDim.x;
  for (int t = i; t < total; t += stride) {
    int seg = 0;
    while (seg < 16 && t >= fp.ofs[seg] + fp.len[seg]) ++seg;
    canon[t] = (float)((const FT*)fp.p[seg])[t - fp.ofs[seg]];
  }
}

template <typename IT>
__global__ void k_cvt_idx(const IT* __restrict__ ei, int* __restrict__ eic,
                          const int* __restrict__ flags) {
  if (flags[1] != (int)(sizeof(IT) == 8)) return;
  int i = blockIdx.x * blockDim.x + threadIdx.x;
  int stride = gridDim.x * blockDim.x;
  for (int t = i; t < 2 * NE; t += stride) eic[t] = (int)ei[t];
}

// ---------------- utility: zero fill ----------------
__global__ void k_zero4(f32x4* __restrict__ p, int n4) {
  int i = blockIdx.x * blockDim.x + threadIdx.x;
  int stride = gridDim.x * blockDim.x;
  f32x4 z = {0.f, 0.f, 0.f, 0.f};
  for (int t = i; t < n4; t += stride) p[t] = z;
}

// ---------------- CSR build (dst-major, for GCN gather) ----------------
__global__ void k_count(const int* __restrict__ col, int* __restrict__ cnt) {
  int i = blockIdx.x * blockDim.x + threadIdx.x;
  int stride = gridDim.x * blockDim.x;
  for (int e = i; e < NE; e += stride) atomicAdd(&cnt[col[e]], 1);
}

__global__ void k_dinv(const int* __restrict__ cnt, float* __restrict__ d) {
  int n = blockIdx.x * blockDim.x + threadIdx.x;
  if (n < NN) d[n] = rsqrtf((float)cnt[n] + 1.0f);  // self-loop
}

__global__ void k_scan1(const int* __restrict__ cnt, int* __restrict__ rowptr,
                        int* __restrict__ bsum, int nvals) {
  __shared__ int tmp[256];
  int gid = blockIdx.x * 256 + threadIdx.x;
  int v = (gid < nvals) ? cnt[gid] : 0;
  tmp[threadIdx.x] = v;
  __syncthreads();
  for (int s = 1; s < 256; s <<= 1) {
    int add = (threadIdx.x >= s) ? tmp[threadIdx.x - s] : 0;
    __syncthreads();
    tmp[threadIdx.x] += add;
    __syncthreads();
  }
  if (gid < nvals) rowptr[gid] = tmp[threadIdx.x] - v;
  if (threadIdx.x == 255) bsum[blockIdx.x] = tmp[255];
}

__global__ void k_scan2(int* __restrict__ bsum, int* __restrict__ btop, int nblocks) {
  __shared__ int tmp[512];
  int v = (threadIdx.x < nblocks) ? bsum[threadIdx.x] : 0;
  tmp[threadIdx.x] = v;
  __syncthreads();
  for (int s = 1; s < 512; s <<= 1) {
    int add = (threadIdx.x >= s) ? tmp[threadIdx.x - s] : 0;
    __syncthreads();
    tmp[threadIdx.x] += add;
    __syncthreads();
  }
  if (threadIdx.x < nblocks) btop[threadIdx.x] = tmp[threadIdx.x] - v;
}

__global__ void k_scan3(int* __restrict__ rowptr, const int* __restrict__ btop,
                        int* __restrict__ cursor, int nvals) {
  int gid = blockIdx.x * 256 + threadIdx.x;
  if (gid < nvals) {
    int v = rowptr[gid] + btop[blockIdx.x];
    rowptr[gid] = v;
    cursor[gid] = v;
  }
}

__global__ void k_fill(const int* __restrict__ eic, int* __restrict__ cursor,
                       int* __restrict__ csr_src) {
  int i = blockIdx.x * blockDim.x + threadIdx.x;
  int stride = gridDim.x * blockDim.x;
  for (int e = i; e < NE; e += stride) {
    int src = eic[e], dst = eic[NE + e];
    int pos = atomicAdd(&cursor[dst], 1);
    csr_src[pos] = src;
  }
}

// ---------------- xs = x * dinv (float4-padded) ----------------
__global__ void k_xs(const float* __restrict__ x, const float* __restrict__ dinv,
                     f32x4* __restrict__ xs4) {
  int n = blockIdx.x * blockDim.x + threadIdx.x;
  if (n >= NN) return;
  float d = dinv[n];
  f32x4 r = {x[n * 3 + 0] * d, x[n * 3 + 1] * d, x[n * 3 + 2] * d, 0.f};
  xs4[n] = r;
}

// ---------------- g1: 3-dim aggregate of xs -> agg3 = (sum + self)*dinv ----------------
__global__ __launch_bounds__(256) void k_g1(const int* __restrict__ rowptr,
                                            const int* __restrict__ cnt,
                                            const int* __restrict__ csr_src,
                                            const f32x4* __restrict__ xs4,
                                            const float* __restrict__ dinv,
                                            f32x4* __restrict__ agg3) {
  int wid = (blockIdx.x * blockDim.x + threadIdx.x) >> 6;
  int nw = (gridDim.x * blockDim.x) >> 6;
  int lane = threadIdx.x & 63;
  int comp = lane & 3, slot = lane >> 2;  // 16 slots x 4 comps
  for (int n = wid; n < NN; n += nw) {
    int beg = rowptr[n], c = cnt[n];
    float acc = 0.f;
    for (int k = slot; k < c; k += 16) {
      int src = csr_src[beg + k];
      acc += ((const float*)(xs4 + src))[comp];
    }
    // reduce over slots (lane bits 2..5)
    acc += __shfl_xor(acc, 4); acc += __shfl_xor(acc, 8);
    acc += __shfl_xor(acc, 16); acc += __shfl_xor(acc, 32);
    if (lane < 4) {
      float self = ((const float*)(xs4 + n))[comp];
      ((float*)(agg3 + n))[comp] = (acc + self) * dinv[n];
    }
  }
}

// ---------------- f1: h1 = relu(agg3@W1+b1); hs2 = (h1@W2)*dinv ----------------
__global__ __launch_bounds__(256) void k_f1(const f32x4* __restrict__ agg3,
                                            const float* __restrict__ W1f,
                                            const float* __restrict__ b1f,
                                            const float* __restrict__ W2f,
                                            const float* __restrict__ dinv,
                                            float* __restrict__ hs) {
  __shared__ float W1l[192];
  __shared__ float b1l[64];
  __shared__ float W2l[64 * 64];
  __shared__ float hrow[4][64];
  int tid = threadIdx.x;
  if (tid < 192) W1l[tid] = W1f[tid];
  if (tid < 64) b1l[tid] = b1f[tid];
  for (int i = tid; i < 64 * 64; i += 256) W2l[i] = W2f[i];
  __syncthreads();
  int w = tid >> 6, j = tid & 63;
  for (int nb = blockIdx.x * 4 + w; nb < NN; nb += gridDim.x * 4) {
    f32x4 a = agg3[nb];
    float h = fmaxf(a[0] * W1l[j] + a[1] * W1l[64 + j] + a[2] * W1l[128 + j] + b1l[j], 0.f);
    hrow[w][j] = h;
    LDS_FENCE();
    float acc = 0.f;
#pragma unroll 8
    for (int k = 0; k < 64; ++k) acc += hrow[w][k] * W2l[k * 64 + j];
    hs[nb * 64 + j] = acc * dinv[nb];
  }
}

// ---------------- g2: gather hs2 -> h2 = relu((sum+self)*dinv+b2); hs3 = (h2@W3)*dinv ----------------
__global__ __launch_bounds__(256) void k_g2(const int* __restrict__ rowptr,
                                            const int* __restrict__ cnt,
                                            const int* __restrict__ csr_src,
                                            const float* __restrict__ hs,
                                            const float* __restrict__ dinv,
                                            const float* __restrict__ b2f,
                                            const float* __restrict__ W3f,
                                            float* __restrict__ hs3) {
  __shared__ float W3l[64 * 64];
  __shared__ float hrow[4][64];
  int tid = threadIdx.x;
  for (int i = tid; i < 64 * 64; i += 256) W3l[i] = W3f[i];
  __syncthreads();
  int w = tid >> 6, j = tid & 63;
  float rb = b2f[j];
  for (int n = blockIdx.x * 4 + w; n < NN; n += gridDim.x * 4) {
    int beg = rowptr[n], c = cnt[n];
    float acc = hs[n * 64 + j];  // self
    int k = 0;
    for (; k + 8 <= c; k += 8) {
      int s0 = csr_src[beg + k + 0], s1 = csr_src[beg + k + 1];
      int s2 = csr_src[beg + k + 2], s3 = csr_src[beg + k + 3];
      int s4 = csr_src[beg + k + 4], s5 = csr_src[beg + k + 5];
      int s6 = csr_src[beg + k + 6], s7 = csr_src[beg + k + 7];
      float v0 = hs[s0 * 64 + j], v1 = hs[s1 * 64 + j];
      float v2 = hs[s2 * 64 + j], v3 = hs[s3 * 64 + j];
      float v4 = hs[s4 * 64 + j], v5 = hs[s5 * 64 + j];
      float v6 = hs[s6 * 64 + j], v7 = hs[s7 * 64 + j];
      acc += ((v0 + v1) + (v2 + v3)) + ((v4 + v5) + (v6 + v7));
    }
    for (; k < c; ++k) acc += hs[csr_src[beg + k] * 64 + j];
    float h2 = fmaxf(acc * dinv[n] + rb, 0.f);
    hrow[w][j] = h2;
    LDS_FENCE();
    float s = 0.f;
#pragma unroll 8
    for (int kk = 0; kk < 64; ++kk) s += hrow[w][kk] * W3l[kk * 64 + j];
    hs3[n * 64 + j] = s * dinv[n];
  }
}

// ---------------- g3: gather hs3 -> h3 = (sum+self)*dinv+b3; u,v = h3 @ Wm1 halves ----------------
__global__ __launch_bounds__(256) void k_g3(const int* __restrict__ rowptr,
                                            const int* __restrict__ cnt,
                                            const int* __restrict__ csr_src,
                                            const float* __restrict__ hs3,
                                            const float* __restrict__ dinv,
                                            const float* __restrict__ b3f,
                                            const float* __restrict__ Wm1f,
                                            bf16_t* __restrict__ u, bf16_t* __restrict__ v) {
  __shared__ float Wt[64 * 64];
  __shared__ float Wb[64 * 64];
  __shared__ float hrow[4][64];
  int tid = threadIdx.x;
  for (int i = tid; i < 64 * 64; i += 256) {
    Wt[i] = Wm1f[i];
    Wb[i] = Wm1f[4096 + i];
  }
  __syncthreads();
  int w = tid >> 6, j = tid & 63;
  float rb = b3f[j];
  for (int n = blockIdx.x * 4 + w; n < NN; n += gridDim.x * 4) {
    int beg = rowptr[n], c = cnt[n];
    float acc = hs3[n * 64 + j];  // self
    int k = 0;
    for (; k + 8 <= c; k += 8) {
      int s0 = csr_src[beg + k + 0], s1 = csr_src[beg + k + 1];
      int s2 = csr_src[beg + k + 2], s3 = csr_src[beg + k + 3];
      int s4 = csr_src[beg + k + 4], s5 = csr_src[beg + k + 5];
      int s6 = csr_src[beg + k + 6], s7 = csr_src[beg + k + 7];
      float v0 = hs3[s0 * 64 + j], v1 = hs3[s1 * 64 + j];
      float v2 = hs3[s2 * 64 + j], v3 = hs3[s3 * 64 + j];
      float v4 = hs3[s4 * 64 + j], v5 = hs3[s5 * 64 + j];
      float v6 = hs3[s6 * 64 + j], v7 = hs3[s7 * 64 + j];
      acc += ((v0 + v1) + (v2 + v3)) + ((v4 + v5) + (v6 + v7));
    }
    for (; k < c; ++k) acc += hs3[csr_src[beg + k] * 64 + j];
    float h3 = acc * dinv[n] + rb;  // no relu
    hrow[w][j] = h3;
    LDS_FENCE();
    float au = 0.f, av = 0.f;
#pragma unroll 8
    for (int kk = 0; kk < 64; ++kk) {
      float hv = hrow[w][kk];
      au += hv * Wt[kk * 64 + j];
      av += hv * Wb[kk * 64 + j];
    }
    u[n * 64 + j] = (bf16_t)au;
    v[n * 64 + j] = (bf16_t)av;
  }
}

// ============ pass 1: BN1 stats of a1 = relu(u[src]+v[dst]+bm1) ============
__global__ __launch_bounds__(256) void k_e1(const int* __restrict__ eic,
                                            const bf16_t* __restrict__ u,
                                            const bf16_t* __restrict__ v,
                                            const float* __restrict__ bm1f,
                                            float* __restrict__ sum1,
                                            float* __restrict__ sq1) {
  __shared__ float reds[16][16];
  __shared__ float redq[16][16];
  int lane = threadIdx.x & 63;
  int wv = threadIdx.x >> 6;
  int wave = blockIdx.x * 4 + wv;
  int nwaves = gridDim.x * 4;
  int n = lane & 15, q = lane >> 4;
  f32x16 bk;
#pragma unroll
  for (int j = 0; j < 8; ++j) {
    bk[j] = bm1f[q * 8 + j];
    bk[8 + j] = bm1f[32 + q * 8 + j];
  }
  f32x16 accs = {};
  f32x16 accq = {};
#pragma unroll 2
  for (int t = wave; t < NE / 16; t += nwaves) {
    int e = t * 16 + n;
    int src = eic[e], dst = eic[NE + e];
    const bf16x8* pu = (const bf16x8*)(u + src * 64);
    const bf16x8* pv = (const bf16x8*)(v + dst * 64);
    bf16x8 ua = pu[q], ub = pu[4 + q], va = pv[q], vb = pv[4 + q];
    f32x16 a1k;
#pragma unroll
    for (int j = 0; j < 8; ++j) {
      a1k[j] = fmaxf((float)ua[j] + (float)va[j] + bk[j], 0.f);
      a1k[8 + j] = fmaxf((float)ub[j] + (float)vb[j] + bk[8 + j], 0.f);
    }
    accs += a1k;
    accq += a1k * a1k;
  }
#pragma unroll
  for (int j = 0; j < 16; ++j) {
    float s = accs[j], qq = accq[j];
    s += __shfl_xor(s, 1); s += __shfl_xor(s, 2);
    s += __shfl_xor(s, 4); s += __shfl_xor(s, 8);
    qq += __shfl_xor(qq, 1); qq += __shfl_xor(qq, 2);
    qq += __shfl_xor(qq, 4); qq += __shfl_xor(qq, 8);
    if (n == 0) {
      reds[wv * 4 + q][j] = s;
      redq[wv * 4 + q][j] = qq;
    }
  }
  __syncthreads();
  int tid = threadIdx.x;
  if (tid < 64) {
    int jq = (tid & 31) >> 3, elem = (tid >> 5) * 8 + (tid & 7);
    float s = reds[jq][elem] + reds[4 + jq][elem] + reds[8 + jq][elem] + reds[12 + jq][elem];
    float qq = redq[jq][elem] + redq[4 + jq][elem] + redq[8 + jq][elem] + redq[12 + jq][elem];
    unsafeAtomicAdd(&sum1[tid], s);
    unsafeAtomicAdd(&sq1[tid], qq);
  }
}

// ---------------- BN affine constants ----------------
__global__ void k_bnconst(const float* __restrict__ sum, const float* __restrict__ sq,
                          const float* __restrict__ g, const float* __restrict__ be,
                          float* __restrict__ sarr, float* __restrict__ tarr, int ncol) {
  int j = threadIdx.x;
  if (j >= ncol) return;
  float mu = sum[j] / (float)NE;
  float var = fmaxf(sq[j] / (float)NE - mu * mu, 0.f);
  float s = g[j] * rsqrtf(var + EPS);
  sarr[j] = s;
  tarr[j] = be[j] - mu * s;
}

// ============ pass 2: BN2 stats of a2 (+ optional store of pre-BN a2) ============
template <bool STORE>
__global__ __launch_bounds__(256) void k_e2(const int* __restrict__ eic,
                                            const bf16_t* __restrict__ u,
                                            const bf16_t* __restrict__ v,
                                            const float* __restrict__ bm1f,
                                            const float* __restrict__ s1, const float* __restrict__ t1,
                                            const float* __restrict__ Wm2f,
                                            const float* __restrict__ bm2f,
                                            bf16_t* __restrict__ a2s,
                                            float* __restrict__ sum2,
                                            float* __restrict__ sq2) {
  __shared__ float red2[4][4][16];  // [wv][{s0,q0,s1,q1}][n]
  int lane = threadIdx.x & 63;
  int wv = threadIdx.x >> 6;
  int wave = blockIdx.x * 4 + wv;
  int nwaves = gridDim.x * 4;
  int n = lane & 15, q = lane >> 4;
  f32x16 bk, s1k, t1k;
#pragma unroll
  for (int j = 0; j < 8; ++j) {
    bk[j] = bm1f[q * 8 + j];       bk[8 + j] = bm1f[32 + q * 8 + j];
    s1k[j] = s1[q * 8 + j];        s1k[8 + j] = s1[32 + q * 8 + j];
    t1k[j] = t1[q * 8 + j];        t1k[8 + j] = t1[32 + q * 8 + j];
  }
  bf16x8 b2h00, b2h01, b2h10, b2h11;
#pragma unroll
  for (int j = 0; j < 8; ++j) {
    b2h00[j] = (bf16_t)Wm2f[(q * 8 + j) * 32 + 0 * 16 + n];
    b2h01[j] = (bf16_t)Wm2f[(q * 8 + j) * 32 + 1 * 16 + n];
    b2h10[j] = (bf16_t)Wm2f[(32 + q * 8 + j) * 32 + 0 * 16 + n];
    b2h11[j] = (bf16_t)Wm2f[(32 + q * 8 + j) * 32 + 1 * 16 + n];
  }
  float bias20 = bm2f[n], bias21 = bm2f[16 + n];
  float accs0 = 0.f, accs1 = 0.f, accq0 = 0.f, accq1 = 0.f;
  for (int t = wave; t < NE / 16; t += nwaves) {
    int e = t * 16 + n;
    int src = eic[e], dst = eic[NE + e];
    const bf16x8* pu = (const bf16x8*)(u + src * 64);
    const bf16x8* pv = (const bf16x8*)(v + dst * 64);
    bf16x8 ua = pu[q], ub = pu[4 + q], va = pv[q], vb = pv[4 + q];
    f32x16 a1k;
#pragma unroll
    for (int j = 0; j < 8; ++j) {
      a1k[j] = fmaxf((float)ua[j] + (float)va[j] + bk[j], 0.f);
      a1k[8 + j] = fmaxf((float)ub[j] + (float)vb[j] + bk[8 + j], 0.f);
    }
    f32x16 z = a1k * s1k + t1k;
    bf16x8 g0h, g0l, g1h, g1l;
#pragma unroll
    for (int j = 0; j < 8; ++j) {
      float z0 = z[j], z1 = z[8 + j];
      bf16_t h0 = (bf16_t)z0, h1 = (bf16_t)z1;
      g0h[j] = h0; g0l[j] = (bf16_t)(z0 - (float)h0);
      g1h[j] = h1; g1l[j] = (bf16_t)(z1 - (float)h1);
    }
    f32x4 c0 = {0.f, 0.f, 0.f, 0.f}, c1 = {0.f, 0.f, 0.f, 0.f};
    c0 = __builtin_amdgcn_mfma_f32_16x16x32_bf16(g0h, b2h00, c0, 0, 0, 0);
    c0 = __builtin_amdgcn_mfma_f32_16x16x32_bf16(g0l, b2h00, c0, 0, 0, 0);
    c0 = __builtin_amdgcn_mfma_f32_16x16x32_bf16(g1h, b2h10, c0, 0, 0, 0);
    c0 = __builtin_amdgcn_mfma_f32_16x16x32_bf16(g1l, b2h10, c0, 0, 0, 0);
    c1 = __builtin_amdgcn_mfma_f32_16x16x32_bf16(g0h, b2h01, c1, 0, 0, 0);
    c1 = __builtin_amdgcn_mfma_f32_16x16x32_bf16(g0l, b2h01, c1, 0, 0, 0);
    c1 = __builtin_amdgcn_mfma_f32_16x16x32_bf16(g1h, b2h11, c1, 0, 0, 0);
    c1 = __builtin_amdgcn_mfma_f32_16x16x32_bf16(g1l, b2h11, c1, 0, 0, 0);
#pragma unroll
    for (int r = 0; r < 4; ++r) {
      float v0 = fmaxf(c0[r] + bias20, 0.f);
      float v1 = fmaxf(c1[r] + bias21, 0.f);
      if (STORE) {
        a2s[(size_t)(t * 16 + q * 4 + r) * 32 + n] = (bf16_t)v0;
        a2s[(size_t)(t * 16 + q * 4 + r) * 32 + 16 + n] = (bf16_t)v1;
      }
      accs0 += v0; accq0 += v0 * v0;
      accs1 += v1; accq1 += v1 * v1;
    }
  }
  accs0 += __shfl_xor(accs0, 16); accs0 += __shfl_xor(accs0, 32);
  accq0 += __shfl_xor(accq0, 16); accq0 += __shfl_xor(accq0, 32);
  accs1 += __shfl_xor(accs1, 16); accs1 += __shfl_xor(accs1, 32);
  accq1 += __shfl_xor(accq1, 16); accq1 += __shfl_xor(accq1, 32);
  if (lane < 16) {
    red2[wv][0][lane] = accs0;
    red2[wv][1][lane] = accq0;
    red2[wv][2][lane] = accs1;
    red2[wv][3][lane] = accq1;
  }
  __syncthreads();
  int tid = threadIdx.x;
  if (tid < 32) {
    int which = tid >> 4, nn = tid & 15;
    float s = red2[0][which * 2][nn] + red2[1][which * 2][nn] + red2[2][which * 2][nn] +
              red2[3][which * 2][nn];
    float qq = red2[0][which * 2 + 1][nn] + red2[1][which * 2 + 1][nn] +
               red2[2][which * 2 + 1][nn] + red2[3][which * 2 + 1][nn];
    unsafeAtomicAdd(&sum2[tid], s);
    unsafeAtomicAdd(&sq2[tid], qq);
  }
}

// ============ pass 3 tier B: stream stored a2 (original order) -> out ============
template <typename OT>
__global__ __launch_bounds__(256) void k_out_stream(const bf16_t* __restrict__ a2s,
                                                    const float* __restrict__ s2,
                                                    const float* __restrict__ t2,
                                                    const float* __restrict__ Wm3f,
                                                    const float* __restrict__ bm3f,
                                                    OT* __restrict__ out,
                                                    const int* __restrict__ flags) {
  if (flags[0] != (int)(sizeof(OT) == 2)) return;
  int lane = threadIdx.x & 63;
  int wave = blockIdx.x * 4 + (threadIdx.x >> 6);
  int nwaves = gridDim.x * 4;
  int half = lane & 1;
  int sub = lane >> 1;  // 0..31
  f32x16 s2c, t2c, w0, w1;
#pragma unroll
  for (int i = 0; i < 16; ++i) {
    int c = half * 16 + i;
    s2c[i] = s2[c]; t2c[i] = t2[c];
    w0[i] = Wm3f[c * 2 + 0]; w1[i] = Wm3f[c * 2 + 1];
  }
  float bb0 = bm3f[0], bb1 = bm3f[1];
  const int ntiles = NE / 32;
#pragma unroll 2
  for (int t = wave; t < ntiles; t += nwaves) {
    int e = t * 32 + sub;
    const bf16x8* pa = (const bf16x8*)(a2s + (size_t)e * 32 + half * 16);
    bf16x8 v0 = pa[0], v1 = pa[1];
    float o0 = 0.f, o1 = 0.f;
#pragma unroll
    for (int i = 0; i < 8; ++i) {
      float z = (float)v0[i] * s2c[i] + t2c[i];
      o0 += z * w0[i]; o1 += z * w1[i];
      float z2 = (float)v1[i] * s2c[8 + i] + t2c[8 + i];
      o0 += z2 * w0[8 + i]; o1 += z2 * w1[8 + i];
    }
    o0 += __shfl_xor(o0, 1);
    o1 += __shfl_xor(o1, 1);
    if (half == 0) {
      o0 += bb0; o1 += bb1;
      if (sizeof(OT) == 2) {
        bf16_t p[2] = {(bf16_t)o0, (bf16_t)o1};
        unsigned pw;
        memcpy(&pw, p, 4);
        ((unsigned*)out)[e] = pw;
      } else {
        f32x2 pw = {o0, o1};
        ((f32x2*)out)[e] = pw;
      }
    }
  }
}

// ============ pass 3 tier C: recompute a2 and reduce -> out ============
template <typename OT>
__global__ __launch_bounds__(256) void k_out_recomp(const int* __restrict__ eic,
                                                    const bf16_t* __restrict__ u,
                                                    const bf16_t* __restrict__ v,
                                                    const float* __restrict__ bm1f,
                                                    const float* __restrict__ s1, const float* __restrict__ t1,
                                                    const float* __restrict__ Wm2f,
                                                    const float* __restrict__ bm2f,
                                                    const float* __restrict__ s2, const float* __restrict__ t2,
                                                    const float* __restrict__ Wm3f,
                                                    const float* __restrict__ bm3f,
                                                    OT* __restrict__ out,
                                                    const int* __restrict__ flags) {
  if (flags[0] != (int)(sizeof(OT) == 2)) return;
  int lane = threadIdx.x & 63;
  int wave = blockIdx.x * 4 + (threadIdx.x >> 6);
  int nwaves = gridDim.x * 4;
  int n = lane & 15, q = lane >> 4;
  f32x16 bk, s1k, t1k;
#pragma unroll
  for (int j = 0; j < 8; ++j) {
    bk[j] = bm1f[q * 8 + j];       bk[8 + j] = bm1f[32 + q * 8 + j];
    s1k[j] = s1[q * 8 + j];        s1k[8 + j] = s1[32 + q * 8 + j];
    t1k[j] = t1[q * 8 + j];        t1k[8 + j] = t1[32 + q * 8 + j];
  }
  bf16x8 b2h00, b2h01, b2h10, b2h11;
#pragma unroll
  for (int j = 0; j < 8; ++j) {
    b2h00[j] = (bf16_t)Wm2f[(q * 8 + j) * 32 + 0 * 16 + n];
    b2h01[j] = (bf16_t)Wm2f[(q * 8 + j) * 32 + 1 * 16 + n];
    b2h10[j] = (bf16_t)Wm2f[(32 + q * 8 + j) * 32 + 0 * 16 + n];
    b2h11[j] = (bf16_t)Wm2f[(32 + q * 8 + j) * 32 + 1 * 16 + n];
  }
  float bias20 = bm2f[n], bias21 = bm2f[16 + n];
  float s2c0 = s2[n], t2c0 = t2[n], s2c1 = s2[16 + n], t2c1 = t2[16 + n];
  float w3a0 = Wm3f[n * 2 + 0], w3a1 = Wm3f[n * 2 + 1];
  float w3b0 = Wm3f[(16 + n) * 2 + 0], w3b1 = Wm3f[(16 + n) * 2 + 1];
  float bb0 = bm3f[0], bb1 = bm3f[1];

  for (int t = wave; t < NE / 16; t += nwaves) {
    int e = t * 16 + n;
    int src = eic[e], dst = eic[NE + e];
    const bf16x8* pu = (const bf16x8*)(u + src * 64);
    const bf16x8* pv = (const bf16x8*)(v + dst * 64);
    bf16x8 ua = pu[q], ub = pu[4 + q], va = pv[q], vb = pv[4 + q];
    f32x16 a1k;
#pragma unroll
    for (int j = 0; j < 8; ++j) {
      a1k[j] = fmaxf((float)ua[j] + (float)va[j] + bk[j], 0.f);
      a1k[8 + j] = fmaxf((float)ub[j] + (float)vb[j] + bk[8 + j], 0.f);
    }
    f32x16 z = a1k * s1k + t1k;
    bf16x8 g0h, g0l, g1h, g1l;
#pragma unroll
    for (int j = 0; j < 8; ++j) {
      float z0 = z[j], z1 = z[8 + j];
      bf16_t h0 = (bf16_t)z0, h1 = (bf16_t)z1;
      g0h[j] = h0; g0l[j] = (bf16_t)(z0 - (float)h0);
      g1h[j] = h1; g1l[j] = (bf16_t)(z1 - (float)h1);
    }
    f32x4 c0 = {0.f, 0.f, 0.f, 0.f}, c1 = {0.f, 0.f, 0.f, 0.f};
    c0 = __builtin_amdgcn_mfma_f32_16x16x32_bf16(g0h, b2h00, c0, 0, 0, 0);
    c0 = __builtin_amdgcn_mfma_f32_16x16x32_bf16(g0l, b2h00, c0, 0, 0, 0);
    c0 = __builtin_amdgcn_mfma_f32_16x16x32_bf16(g1h, b2h10, c0, 0, 0, 0);
    c0 = __builtin_amdgcn_mfma_f32_16x16x32_bf16(g1l, b2h10, c0, 0, 0, 0);
    c1 = __builtin_amdgcn_mfma_f32_16x16x32_bf16(g0h, b2h01, c1, 0, 0, 0);
    c1 = __builtin_amdgcn_mfma_f32_16x16x32_bf16(g0l, b2h01, c1, 0, 0, 0);
    c1 = __builtin_amdgcn_mfma_f32_16x16x32_bf16(g1h, b2h11, c1, 0, 0, 0);
    c1 = __builtin_amdgcn_mfma_f32_16x16x32_bf16(g1l, b2h11, c1, 0, 0, 0);
#pragma unroll
    for (int r = 0; r < 4; ++r) {
      float z0 = fmaxf(c0[r] + bias20, 0.f) * s2c0 + t2c0;
      float z1 = fmaxf(c1[r] + bias21, 0.f) * s2c1 + t2c1;
      float o0 = z0 * w3a0 + z1 * w3b0;
      float o1 = z0 * w3a1 + z1 * w3b1;
      o0 += __shfl_xor(o0, 1); o0 += __shfl_xor(o0, 2);
      o0 += __shfl_xor(o0, 4); o0 += __shfl_xor(o0, 8);
      o1 += __shfl_xor(o1, 1); o1 += __shfl_xor(o1, 2);
      o1 += __shfl_xor(o1, 4); o1 += __shfl_xor(o1, 8);
      if (n == 0) {
        int eo = t * 16 + q * 4 + r;
        o0 += bb0; o1 += bb1;
        if (sizeof(OT) == 2) {
          bf16_t p[2] = {(bf16_t)o0, (bf16_t)o1};
          unsigned pw;
          memcpy(&pw, p, 4);
          ((unsigned*)out)[eo] = pw;
        } else {
          f32x2 pw = {o0, o1};
          ((f32x2*)out)[eo] = pw;
        }
      }
    }
  }
}

// ---------------- host ----------------
extern "C" void kernel_launch(void* const* d_in, const int* in_sizes, int n_in,
                              void* d_out, int out_size, void* d_ws, size_t ws_size,
                              hipStream_t stream) {
  (void)n_in; (void)in_sizes; (void)out_size;

  char* ws = (char*)d_ws;
  size_t off = 0;
  auto alloc = [&](size_t bytes) {
    size_t r = off;
    off = (off + bytes + 255) & ~(size_t)255;
    return r;
  };
  float* dinv  = (float*)(ws + alloc((size_t)NN * 4));
  float* hs    = (float*)(ws + alloc((size_t)NN * HID * 4));
  float* agg   = (float*)(ws + alloc((size_t)NN * HID * 4));  // hs3
  int*   eic   = (int*)(ws + alloc((size_t)2 * NE * 4));
  float* stats = (float*)(ws + alloc(192 * 4));
  float* sum1 = stats, *sq1 = stats + 64, *sum2 = stats + 128, *sq2 = stats + 160;
  int*   flags = (int*)(ws + alloc(256));
  float* s1arr = (float*)(ws + alloc(64 * 4));
  float* t1arr = (float*)(ws + alloc(64 * 4));
  float* s2arr = (float*)(ws + alloc(32 * 4));
  float* t2arr = (float*)(ws + alloc(32 * 4));
  // dst-CSR (GCN gather)
  int* cnt     = (int*)(ws + alloc((size_t)NN * 4));
  int* rowptr  = (int*)(ws + alloc((size_t)NN * 4));
  int* cursor  = (int*)(ws + alloc((size_t)NN * 4));
  int* bsum    = (int*)(ws + alloc(512 * 4));
  int* btop    = (int*)(ws + alloc(512 * 4));
  int* csr_src = (int*)(ws + alloc((size_t)NE * 4));
  // node-level MLP factors + 3-dim staging
  bf16_t* u    = (bf16_t*)(ws + alloc((size_t)NN * HID * 2));
  bf16_t* v    = (bf16_t*)(ws + alloc((size_t)NN * HID * 2));
  f32x4* xs4   = (f32x4*)(ws + alloc((size_t)NN * 16));
  f32x4* agg3  = (f32x4*)(ws + alloc((size_t)NN * 16));

  // canonical f32 input block
  static const int flens[17] = {NN * 3, 3 * 64, 64, 64 * 64, 64, 64 * 64, 64,
                                128 * 64, 64, 64, 64, 64 * 32, 32, 32, 32, 32 * 2, 2};
  FPtrs fp;
  int total_f = 0;
  {
    int fi = 0;
    for (int i = 0; i < 18; ++i) {
      if (i == 1) continue;
      fp.p[fi] = d_in[i];
      fp.len[fi] = flens[fi];
      fp.ofs[fi] = total_f;
      total_f += flens[fi];
      ++fi;
    }
  }
  float* canon = (float*)(ws + alloc((size_t)total_f * 4));
  size_t a2_off = alloc((size_t)NE * 32 * 2);
  bf16_t* a2s = (bf16_t*)(ws + a2_off);
  bool tierB = (a2_off + (size_t)NE * 32 * 2) <= ws_size;

  const float* xf   = canon + fp.ofs[0];
  const float* W1f  = canon + fp.ofs[1];
  const float* b1f  = canon + fp.ofs[2];
  const float* W2f  = canon + fp.ofs[3];
  const float* b2f  = canon + fp.ofs[4];
  const float* W3f  = canon + fp.ofs[5];
  const float* b3f  = canon + fp.ofs[6];
  const float* Wm1f = canon + fp.ofs[7];
  const float* bm1f = canon + fp.ofs[8];
  const float* g1f  = canon + fp.ofs[9];
  const float* be1f = canon + fp.ofs[10];
  const float* Wm2f = canon + fp.ofs[11];
  const float* bm2f = canon + fp.ofs[12];
  const float* g2f  = canon + fp.ofs[13];
  const float* be2f = canon + fp.ofs[14];
  const float* Wm3f = canon + fp.ofs[15];
  const float* bm3f = canon + fp.ofs[16];

  const int nscanb = (NN + 255) / 256;  // 391

  // 0) detect dtypes, canonicalize
  k_detect<<<1, 64, 0, stream>>>((const unsigned*)d_in[0], (const int*)d_in[1], flags);
  k_cvt_idx<int><<<1600, 256, 0, stream>>>((const int*)d_in[1], eic, flags);
  k_cvt_idx<long long><<<1600, 256, 0, stream>>>((const long long*)d_in[1], eic, flags);
  k_cvt_f<float><<<640, 256, 0, stream>>>(fp, canon, flags, total_f);
  k_cvt_f<bf16_t><<<640, 256, 0, stream>>>(fp, canon, flags, total_f);

  // 1) CSR build + dinv + stats zero
  k_zero4<<<128, 256, 0, stream>>>((f32x4*)cnt, NN / 4);
  k_zero4<<<1, 64, 0, stream>>>((f32x4*)stats, 48);
  k_count<<<1600, 256, 0, stream>>>(eic + NE, cnt);
  k_dinv<<<(NN + 255) / 256, 256, 0, stream>>>(cnt, dinv);
  k_scan1<<<nscanb, 256, 0, stream>>>(cnt, rowptr, bsum, NN);
  k_scan2<<<1, 512, 0, stream>>>(bsum, btop, nscanb);
  k_scan3<<<nscanb, 256, 0, stream>>>(rowptr, btop, cursor, NN);
  k_fill<<<1600, 256, 0, stream>>>(eic, cursor, csr_src);

  // ---- GCN layer 1 (3-dim aggregation; aggregation commutes with @W1) ----
  k_xs<<<(NN + 255) / 256, 256, 0, stream>>>(xf, dinv, xs4);
  k_g1<<<2048, 256, 0, stream>>>(rowptr, cnt, csr_src, xs4, dinv, agg3);
  k_f1<<<2048, 256, 0, stream>>>(agg3, W1f, b1f, W2f, dinv, hs);  // hs2

  // ---- GCN layer 2 (gather + fused @W3*dinv) ----
  k_g2<<<2048, 256, 0, stream>>>(rowptr, cnt, csr_src, hs, dinv, b2f, W3f, agg);  // hs3

  // ---- GCN layer 3 (gather + fused @Wm1 halves -> u,v) ----
  k_g3<<<2048, 256, 0, stream>>>(rowptr, cnt, csr_src, agg, dinv, b3f, Wm1f, u, v);

  // ---- edge MLP ----
  k_e1<<<2048, 256, 0, stream>>>(eic, u, v, bm1f, sum1, sq1);
  k_bnconst<<<1, 64, 0, stream>>>(sum1, sq1, g1f, be1f, s1arr, t1arr, 64);
  if (tierB) {
    k_e2<true><<<2048, 256, 0, stream>>>(eic, u, v, bm1f, s1arr, t1arr, Wm2f, bm2f, a2s,
                                         sum2, sq2);
    k_bnconst<<<1, 64, 0, stream>>>(sum2, sq2, g2f, be2f, s2arr, t2arr, 32);
    k_out_stream<float><<<2048, 256, 0, stream>>>(a2s, s2arr, t2arr, Wm3f, bm3f,
                                                  (float*)d_out, flags);
    k_out_stream<bf16_t><<<2048, 256, 0, stream>>>(a2s, s2arr, t2arr, Wm3f, bm3f,
                                                   (bf16_t*)d_out, flags);
  } else {
    k_e2<false><<<2048, 256, 0, stream>>>(eic, u, v, bm1f, s1arr, t1arr, Wm2f, bm2f, a2s,
                                          sum2, sq2);
    k_bnconst<<<1, 64, 0, stream>>>(sum2, sq2, g2f, be2f, s2arr, t2arr, 32);
    k_out_recomp<float><<<2048, 256, 0, stream>>>(eic, u, v, bm1f, s1arr, t1arr, Wm2f,
                                                  bm2f, s2arr, t2arr, Wm3f, bm3f,
                                                  (float*)d_out, flags);
    k_out_recomp<bf16_t><<<2048, 256, 0, stream>>>(eic, u, v, bm1f, s1arr, t1arr, Wm2f,
                                                   bm2f, s2arr, t2arr, Wm3f, bm3f,
                                                   (bf16_t*)d_out, flags);
  }
}

// Round 12
// 780.617 us; speedup vs baseline: 3.3016x; 1.0661x over previous
//
#include <hip/hip_runtime.h>
#include <hip/hip_bf16.h>
#include <cstdint>
#include <cstring>

#define NN 100000
#define NE 1600000
#define HID 64
#define EPS 1e-5f

typedef __bf16 bf16_t;
typedef __attribute__((ext_vector_type(8))) __bf16 bf16x8;
typedef __attribute__((ext_vector_type(4))) float f32x4;
typedef __attribute__((ext_vector_type(2))) float f32x2;
typedef __attribute__((ext_vector_type(16))) float f32x16;

#define LDS_FENCE() asm volatile("s_waitcnt lgkmcnt(0)" ::: "memory")

// ---------------- dtype detectors ----------------
__global__ void k_detect(const unsigned* __restrict__ xw, const int* __restrict__ eiw,
                         int* __restrict__ flags) {
  int lane = threadIdx.x;  // 64
  unsigned u = xw[lane];
  unsigned lo = u & 0xFFFFu;
  unsigned e = (lo >> 7) & 0xFFu;
  bool bf_ok = (lo == 0u) || (e >= 0x50u && e <= 0x8Fu);
  unsigned long long b1 = __ballot(bf_ok);
  int v = eiw[2 * lane + 1];
  unsigned long long b2 = __ballot(v == 0);
  if (lane == 0) {
    flags[0] = (b1 == ~0ull) ? 1 : 0;
    flags[1] = (b2 == ~0ull) ? 1 : 0;
  }
}

// ---------------- input canonicalization ----------------
struct FPtrs {
  const void* p[17];
  int len[17];
  int ofs[17];
};

template <typename FT>
__global__ void k_cvt_f(FPtrs fp, float* __restrict__ canon, const int* __restrict__ flags,
                        int total) {
  if (flags[0] != (int)(sizeof(FT) == 2)) return;
  int i = blockIdx.x * blockDim.x + threadIdx.x;
  int stride = gridDim.x * blockDim.x;
  for (int t = i; t < total; t += stride) {
    int seg = 0;
    while (seg < 16 && t >= fp.ofs[seg] + fp.len[seg]) ++seg;
    canon[t] = (float)((const FT*)fp.p[seg])[t - fp.ofs[seg]];
  }
}

template <typename IT>
__global__ void k_cvt_idx(const IT* __restrict__ ei, int* __restrict__ eic,
                          const int* __restrict__ flags) {
  if (flags[1] != (int)(sizeof(IT) == 8)) return;
  int i = blockIdx.x * blockDim.x + threadIdx.x;
  int stride = gridDim.x * blockDim.x;
  for (int t = i; t < 2 * NE; t += stride) eic[t] = (int)ei[t];
}

// ---------------- utility: zero fill ----------------
__global__ void k_zero4(f32x4* __restrict__ p, int n4) {
  int i = blockIdx.x * blockDim.x + threadIdx.x;
  int stride = gridDim.x * blockDim.x;
  f32x4 z = {0.f, 0.f, 0.f, 0.f};
  for (int t = i; t < n4; t += stride) p[t] = z;
}

// ---------------- CSR build (dst-major, for GCN gather) ----------------
__global__ void k_count(const int* __restrict__ col, int* __restrict__ cnt) {
  int i = blockIdx.x * blockDim.x + threadIdx.x;
  int stride = gridDim.x * blockDim.x;
  for (int e = i; e < NE; e += stride) atomicAdd(&cnt[col[e]], 1);
}

__global__ void k_dinv(const int* __restrict__ cnt, float* __restrict__ d) {
  int n = blockIdx.x * blockDim.x + threadIdx.x;
  if (n < NN) d[n] = rsqrtf((float)cnt[n] + 1.0f);  // self-loop
}

__global__ void k_scan1(const int* __restrict__ cnt, int* __restrict__ rowptr,
                        int* __restrict__ bsum, int nvals) {
  __shared__ int tmp[256];
  int gid = blockIdx.x * 256 + threadIdx.x;
  int v = (gid < nvals) ? cnt[gid] : 0;
  tmp[threadIdx.x] = v;
  __syncthreads();
  for (int s = 1; s < 256; s <<= 1) {
    int add = (threadIdx.x >= s) ? tmp[threadIdx.x - s] : 0;
    __syncthreads();
    tmp[threadIdx.x] += add;
    __syncthreads();
  }
  if (gid < nvals) rowptr[gid] = tmp[threadIdx.x] - v;
  if (threadIdx.x == 255) bsum[blockIdx.x] = tmp[255];
}

__global__ void k_scan2(int* __restrict__ bsum, int* __restrict__ btop, int nblocks) {
  __shared__ int tmp[512];
  int v = (threadIdx.x < nblocks) ? bsum[threadIdx.x] : 0;
  tmp[threadIdx.x] = v;
  __syncthreads();
  for (int s = 1; s < 512; s <<= 1) {
    int add = (threadIdx.x >= s) ? tmp[threadIdx.x - s] : 0;
    __syncthreads();
    tmp[threadIdx.x] += add;
    __syncthreads();
  }
  if (threadIdx.x < nblocks) btop[threadIdx.x] = tmp[threadIdx.x] - v;
}

__global__ void k_scan3(int* __restrict__ rowptr, const int* __restrict__ btop,
                        int* __restrict__ cursor, int nvals) {
  int gid = blockIdx.x * 256 + threadIdx.x;
  if (gid < nvals) {
    int v = rowptr[gid] + btop[blockIdx.x];
    rowptr[gid] = v;
    cursor[gid] = v;
  }
}

__global__ void k_fill(const int* __restrict__ eic, int* __restrict__ cursor,
                       int* __restrict__ csr_src) {
  int i = blockIdx.x * blockDim.x + threadIdx.x;
  int stride = gridDim.x * blockDim.x;
  for (int e = i; e < NE; e += stride) {
    int src = eic[e], dst = eic[NE + e];
    int pos = atomicAdd(&cursor[dst], 1);
    csr_src[pos] = src;
  }
}

// ---------------- xs = x * dinv (float4-padded) ----------------
__global__ void k_xs(const float* __restrict__ x, const float* __restrict__ dinv,
                     f32x4* __restrict__ xs4) {
  int n = blockIdx.x * blockDim.x + threadIdx.x;
  if (n >= NN) return;
  float d = dinv[n];
  f32x4 r = {x[n * 3 + 0] * d, x[n * 3 + 1] * d, x[n * 3 + 2] * d, 0.f};
  xs4[n] = r;
}

// ---------------- g1: 3-dim aggregate of xs -> agg3 = (sum + self)*dinv ----------------
__global__ __launch_bounds__(256) void k_g1(const int* __restrict__ rowptr,
                                            const int* __restrict__ cnt,
                                            const int* __restrict__ csr_src,
                                            const f32x4* __restrict__ xs4,
                                            const float* __restrict__ dinv,
                                            f32x4* __restrict__ agg3) {
  int wid = (blockIdx.x * blockDim.x + threadIdx.x) >> 6;
  int nw = (gridDim.x * blockDim.x) >> 6;
  int lane = threadIdx.x & 63;
  int comp = lane & 3, slot = lane >> 2;  // 16 slots x 4 comps
  for (int n = wid; n < NN; n += nw) {
    int beg = rowptr[n], c = cnt[n];
    float acc = 0.f;
    for (int k = slot; k < c; k += 16) {
      int src = csr_src[beg + k];
      acc += ((const float*)(xs4 + src))[comp];
    }
    acc += __shfl_xor(acc, 4); acc += __shfl_xor(acc, 8);
    acc += __shfl_xor(acc, 16); acc += __shfl_xor(acc, 32);
    if (lane < 4) {
      float self = ((const float*)(xs4 + n))[comp];
      ((float*)(agg3 + n))[comp] = (acc + self) * dinv[n];
    }
  }
}

// ---------------- f1: h1 = relu(agg3@W1+b1); hs2 = (h1@W2)*dinv  (512 thr, 8 waves) ----------------
__global__ __launch_bounds__(512) void k_f1(const f32x4* __restrict__ agg3,
                                            const float* __restrict__ W1f,
                                            const float* __restrict__ b1f,
                                            const float* __restrict__ W2f,
                                            const float* __restrict__ dinv,
                                            float* __restrict__ hs) {
  __shared__ float W1l[192];
  __shared__ float b1l[64];
  __shared__ float W2l[64 * 64];
  __shared__ float hrow[8][64];
  int tid = threadIdx.x;
  if (tid < 192) W1l[tid] = W1f[tid];
  if (tid < 64) b1l[tid] = b1f[tid];
  for (int i = tid; i < 64 * 64; i += 512) W2l[i] = W2f[i];
  __syncthreads();
  int w = tid >> 6, j = tid & 63;
  for (int nb = blockIdx.x * 8 + w; nb < NN; nb += gridDim.x * 8) {
    f32x4 a = agg3[nb];
    float h = fmaxf(a[0] * W1l[j] + a[1] * W1l[64 + j] + a[2] * W1l[128 + j] + b1l[j], 0.f);
    hrow[w][j] = h;
    LDS_FENCE();
    float acc = 0.f;
#pragma unroll 8
    for (int k = 0; k < 64; ++k) acc += hrow[w][k] * W2l[k * 64 + j];
    hs[nb * 64 + j] = acc * dinv[nb];
  }
}

// ---------------- g2: gather hs2 -> h2 = relu((sum+self)*dinv+b2); hs3 = (h2@W3)*dinv ----------------
__global__ __launch_bounds__(512) void k_g2(const int* __restrict__ rowptr,
                                            const int* __restrict__ cnt,
                                            const int* __restrict__ csr_src,
                                            const float* __restrict__ hs,
                                            const float* __restrict__ dinv,
                                            const float* __restrict__ b2f,
                                            const float* __restrict__ W3f,
                                            float* __restrict__ hs3) {
  __shared__ float W3l[64 * 64];
  __shared__ float hrow[8][64];
  int tid = threadIdx.x;
  for (int i = tid; i < 64 * 64; i += 512) W3l[i] = W3f[i];
  __syncthreads();
  int w = tid >> 6, j = tid & 63;
  float rb = b2f[j];
  for (int n = blockIdx.x * 8 + w; n < NN; n += gridDim.x * 8) {
    int beg = rowptr[n], c = cnt[n];
    float acc = hs[n * 64 + j];  // self
    int k = 0;
    for (; k + 8 <= c; k += 8) {
      int s0 = csr_src[beg + k + 0], s1 = csr_src[beg + k + 1];
      int s2 = csr_src[beg + k + 2], s3 = csr_src[beg + k + 3];
      int s4 = csr_src[beg + k + 4], s5 = csr_src[beg + k + 5];
      int s6 = csr_src[beg + k + 6], s7 = csr_src[beg + k + 7];
      float v0 = hs[s0 * 64 + j], v1 = hs[s1 * 64 + j];
      float v2 = hs[s2 * 64 + j], v3 = hs[s3 * 64 + j];
      float v4 = hs[s4 * 64 + j], v5 = hs[s5 * 64 + j];
      float v6 = hs[s6 * 64 + j], v7 = hs[s7 * 64 + j];
      acc += ((v0 + v1) + (v2 + v3)) + ((v4 + v5) + (v6 + v7));
    }
    for (; k < c; ++k) acc += hs[csr_src[beg + k] * 64 + j];
    float h2 = fmaxf(acc * dinv[n] + rb, 0.f);
    hrow[w][j] = h2;
    LDS_FENCE();
    float s = 0.f;
#pragma unroll 8
    for (int kk = 0; kk < 64; ++kk) s += hrow[w][kk] * W3l[kk * 64 + j];
    hs3[n * 64 + j] = s * dinv[n];
  }
}

// ---------------- g3: gather hs3 -> h3; u,v = h3 @ Wm1 halves  (512 thr, 8 waves) ----------------
__global__ __launch_bounds__(512) void k_g3(const int* __restrict__ rowptr,
                                            const int* __restrict__ cnt,
                                            const int* __restrict__ csr_src,
                                            const float* __restrict__ hs3,
                                            const float* __restrict__ dinv,
                                            const float* __restrict__ b3f,
                                            const float* __restrict__ Wm1f,
                                            bf16_t* __restrict__ u, bf16_t* __restrict__ v) {
  __shared__ float Wt[64 * 64];
  __shared__ float Wb[64 * 64];
  __shared__ float hrow[8][64];
  int tid = threadIdx.x;
  for (int i = tid; i < 64 * 64; i += 512) {
    Wt[i] = Wm1f[i];
    Wb[i] = Wm1f[4096 + i];
  }
  __syncthreads();
  int w = tid >> 6, j = tid & 63;
  float rb = b3f[j];
  for (int n = blockIdx.x * 8 + w; n < NN; n += gridDim.x * 8) {
    int beg = rowptr[n], c = cnt[n];
    float acc = hs3[n * 64 + j];  // self
    int k = 0;
    for (; k + 8 <= c; k += 8) {
      int s0 = csr_src[beg + k + 0], s1 = csr_src[beg + k + 1];
      int s2 = csr_src[beg + k + 2], s3 = csr_src[beg + k + 3];
      int s4 = csr_src[beg + k + 4], s5 = csr_src[beg + k + 5];
      int s6 = csr_src[beg + k + 6], s7 = csr_src[beg + k + 7];
      float v0 = hs3[s0 * 64 + j], v1 = hs3[s1 * 64 + j];
      float v2 = hs3[s2 * 64 + j], v3 = hs3[s3 * 64 + j];
      float v4 = hs3[s4 * 64 + j], v5 = hs3[s5 * 64 + j];
      float v6 = hs3[s6 * 64 + j], v7 = hs3[s7 * 64 + j];
      acc += ((v0 + v1) + (v2 + v3)) + ((v4 + v5) + (v6 + v7));
    }
    for (; k < c; ++k) acc += hs3[csr_src[beg + k] * 64 + j];
    float h3 = acc * dinv[n] + rb;  // no relu
    hrow[w][j] = h3;
    LDS_FENCE();
    float au = 0.f, av = 0.f;
#pragma unroll 8
    for (int kk = 0; kk < 64; ++kk) {
      float hv = hrow[w][kk];
      au += hv * Wt[kk * 64 + j];
      av += hv * Wb[kk * 64 + j];
    }
    u[n * 64 + j] = (bf16_t)au;
    v[n * 64 + j] = (bf16_t)av;
  }
}

// ============ pass 1: BN1 stats of a1 = relu(u[src]+v[dst]+bm1) ============
__global__ __launch_bounds__(256) void k_e1(const int* __restrict__ eic,
                                            const bf16_t* __restrict__ u,
                                            const bf16_t* __restrict__ v,
                                            const float* __restrict__ bm1f,
                                            float* __restrict__ sum1,
                                            float* __restrict__ sq1) {
  __shared__ float reds[16][16];
  __shared__ float redq[16][16];
  int lane = threadIdx.x & 63;
  int wv = threadIdx.x >> 6;
  int wave = blockIdx.x * 4 + wv;
  int nwaves = gridDim.x * 4;
  int n = lane & 15, q = lane >> 4;
  f32x16 bk;
#pragma unroll
  for (int j = 0; j < 8; ++j) {
    bk[j] = bm1f[q * 8 + j];
    bk[8 + j] = bm1f[32 + q * 8 + j];
  }
  f32x16 accs = {};
  f32x16 accq = {};
#pragma unroll 2
  for (int t = wave; t < NE / 16; t += nwaves) {
    int e = t * 16 + n;
    int src = eic[e], dst = eic[NE + e];
    const bf16x8* pu = (const bf16x8*)(u + src * 64);
    const bf16x8* pv = (const bf16x8*)(v + dst * 64);
    bf16x8 ua = pu[q], ub = pu[4 + q], va = pv[q], vb = pv[4 + q];
    f32x16 a1k;
#pragma unroll
    for (int j = 0; j < 8; ++j) {
      a1k[j] = fmaxf((float)ua[j] + (float)va[j] + bk[j], 0.f);
      a1k[8 + j] = fmaxf((float)ub[j] + (float)vb[j] + bk[8 + j], 0.f);
    }
    accs += a1k;
    accq += a1k * a1k;
  }
#pragma unroll
  for (int j = 0; j < 16; ++j) {
    float s = accs[j], qq = accq[j];
    s += __shfl_xor(s, 1); s += __shfl_xor(s, 2);
    s += __shfl_xor(s, 4); s += __shfl_xor(s, 8);
    qq += __shfl_xor(qq, 1); qq += __shfl_xor(qq, 2);
    qq += __shfl_xor(qq, 4); qq += __shfl_xor(qq, 8);
    if (n == 0) {
      reds[wv * 4 + q][j] = s;
      redq[wv * 4 + q][j] = qq;
    }
  }
  __syncthreads();
  int tid = threadIdx.x;
  if (tid < 64) {
    int jq = (tid & 31) >> 3, elem = (tid >> 5) * 8 + (tid & 7);
    float s = reds[jq][elem] + reds[4 + jq][elem] + reds[8 + jq][elem] + reds[12 + jq][elem];
    float qq = redq[jq][elem] + redq[4 + jq][elem] + redq[8 + jq][elem] + redq[12 + jq][elem];
    unsafeAtomicAdd(&sum1[tid], s);
    unsafeAtomicAdd(&sq1[tid], qq);
  }
}

// ---------------- BN affine constants ----------------
__global__ void k_bnconst(const float* __restrict__ sum, const float* __restrict__ sq,
                          const float* __restrict__ g, const float* __restrict__ be,
                          float* __restrict__ sarr, float* __restrict__ tarr, int ncol) {
  int j = threadIdx.x;
  if (j >= ncol) return;
  float mu = sum[j] / (float)NE;
  float var = fmaxf(sq[j] / (float)NE - mu * mu, 0.f);
  float s = g[j] * rsqrtf(var + EPS);
  sarr[j] = s;
  tarr[j] = be[j] - mu * s;
}

// ============ pass 2: BN2 stats of a2 (+ optional store of pre-BN a2) ============
template <bool STORE>
__global__ __launch_bounds__(256) void k_e2(const int* __restrict__ eic,
                                            const bf16_t* __restrict__ u,
                                            const bf16_t* __restrict__ v,
                                            const float* __restrict__ bm1f,
                                            const float* __restrict__ s1, const float* __restrict__ t1,
                                            const float* __restrict__ Wm2f,
                                            const float* __restrict__ bm2f,
                                            bf16_t* __restrict__ a2s,
                                            float* __restrict__ sum2,
                                            float* __restrict__ sq2) {
  __shared__ float red2[4][4][16];  // [wv][{s0,q0,s1,q1}][n]
  int lane = threadIdx.x & 63;
  int wv = threadIdx.x >> 6;
  int wave = blockIdx.x * 4 + wv;
  int nwaves = gridDim.x * 4;
  int n = lane & 15, q = lane >> 4;
  f32x16 bk, s1k, t1k;
#pragma unroll
  for (int j = 0; j < 8; ++j) {
    bk[j] = bm1f[q * 8 + j];       bk[8 + j] = bm1f[32 + q * 8 + j];
    s1k[j] = s1[q * 8 + j];        s1k[8 + j] = s1[32 + q * 8 + j];
    t1k[j] = t1[q * 8 + j];        t1k[8 + j] = t1[32 + q * 8 + j];
  }
  bf16x8 b2h00, b2h01, b2h10, b2h11;
#pragma unroll
  for (int j = 0; j < 8; ++j) {
    b2h00[j] = (bf16_t)Wm2f[(q * 8 + j) * 32 + 0 * 16 + n];
    b2h01[j] = (bf16_t)Wm2f[(q * 8 + j) * 32 + 1 * 16 + n];
    b2h10[j] = (bf16_t)Wm2f[(32 + q * 8 + j) * 32 + 0 * 16 + n];
    b2h11[j] = (bf16_t)Wm2f[(32 + q * 8 + j) * 32 + 1 * 16 + n];
  }
  float bias20 = bm2f[n], bias21 = bm2f[16 + n];
  float accs0 = 0.f, accs1 = 0.f, accq0 = 0.f, accq1 = 0.f;
  for (int t = wave; t < NE / 16; t += nwaves) {
    int e = t * 16 + n;
    int src = eic[e], dst = eic[NE + e];
    const bf16x8* pu = (const bf16x8*)(u + src * 64);
    const bf16x8* pv = (const bf16x8*)(v + dst * 64);
    bf16x8 ua = pu[q], ub = pu[4 + q], va = pv[q], vb = pv[4 + q];
    f32x16 a1k;
#pragma unroll
    for (int j = 0; j < 8; ++j) {
      a1k[j] = fmaxf((float)ua[j] + (float)va[j] + bk[j], 0.f);
      a1k[8 + j] = fmaxf((float)ub[j] + (float)vb[j] + bk[8 + j], 0.f);
    }
    f32x16 z = a1k * s1k + t1k;
    bf16x8 g0h, g0l, g1h, g1l;
#pragma unroll
    for (int j = 0; j < 8; ++j) {
      float z0 = z[j], z1 = z[8 + j];
      bf16_t h0 = (bf16_t)z0, h1 = (bf16_t)z1;
      g0h[j] = h0; g0l[j] = (bf16_t)(z0 - (float)h0);
      g1h[j] = h1; g1l[j] = (bf16_t)(z1 - (float)h1);
    }
    f32x4 c0 = {0.f, 0.f, 0.f, 0.f}, c1 = {0.f, 0.f, 0.f, 0.f};
    c0 = __builtin_amdgcn_mfma_f32_16x16x32_bf16(g0h, b2h00, c0, 0, 0, 0);
    c0 = __builtin_amdgcn_mfma_f32_16x16x32_bf16(g0l, b2h00, c0, 0, 0, 0);
    c0 = __builtin_amdgcn_mfma_f32_16x16x32_bf16(g1h, b2h10, c0, 0, 0, 0);
    c0 = __builtin_amdgcn_mfma_f32_16x16x32_bf16(g1l, b2h10, c0, 0, 0, 0);
    c1 = __builtin_amdgcn_mfma_f32_16x16x32_bf16(g0h, b2h01, c1, 0, 0, 0);
    c1 = __builtin_amdgcn_mfma_f32_16x16x32_bf16(g0l, b2h01, c1, 0, 0, 0);
    c1 = __builtin_amdgcn_mfma_f32_16x16x32_bf16(g1h, b2h11, c1, 0, 0, 0);
    c1 = __builtin_amdgcn_mfma_f32_16x16x32_bf16(g1l, b2h11, c1, 0, 0, 0);
#pragma unroll
    for (int r = 0; r < 4; ++r) {
      float v0 = fmaxf(c0[r] + bias20, 0.f);
      float v1 = fmaxf(c1[r] + bias21, 0.f);
      if (STORE) {
        a2s[(size_t)(t * 16 + q * 4 + r) * 32 + n] = (bf16_t)v0;
        a2s[(size_t)(t * 16 + q * 4 + r) * 32 + 16 + n] = (bf16_t)v1;
      }
      accs0 += v0; accq0 += v0 * v0;
      accs1 += v1; accq1 += v1 * v1;
    }
  }
  accs0 += __shfl_xor(accs0, 16); accs0 += __shfl_xor(accs0, 32);
  accq0 += __shfl_xor(accq0, 16); accq0 += __shfl_xor(accq0, 32);
  accs1 += __shfl_xor(accs1, 16); accs1 += __shfl_xor(accs1, 32);
  accq1 += __shfl_xor(accq1, 16); accq1 += __shfl_xor(accq1, 32);
  if (lane < 16) {
    red2[wv][0][lane] = accs0;
    red2[wv][1][lane] = accq0;
    red2[wv][2][lane] = accs1;
    red2[wv][3][lane] = accq1;
  }
  __syncthreads();
  int tid = threadIdx.x;
  if (tid < 32) {
    int which = tid >> 4, nn = tid & 15;
    float s = red2[0][which * 2][nn] + red2[1][which * 2][nn] + red2[2][which * 2][nn] +
              red2[3][which * 2][nn];
    float qq = red2[0][which * 2 + 1][nn] + red2[1][which * 2 + 1][nn] +
               red2[2][which * 2 + 1][nn] + red2[3][which * 2 + 1][nn];
    unsafeAtomicAdd(&sum2[tid], s);
    unsafeAtomicAdd(&sq2[tid], qq);
  }
}

// ============ pass 3 tier B: stream stored a2 (original order) -> out ============
template <typename OT>
__global__ __launch_bounds__(256) void k_out_stream(const bf16_t* __restrict__ a2s,
                                                    const float* __restrict__ s2,
                                                    const float* __restrict__ t2,
                                                    const float* __restrict__ Wm3f,
                                                    const float* __restrict__ bm3f,
                                                    OT* __restrict__ out,
                                                    const int* __restrict__ flags) {
  if (flags[0] != (int)(sizeof(OT) == 2)) return;
  int lane = threadIdx.x & 63;
  int wave = blockIdx.x * 4 + (threadIdx.x >> 6);
  int nwaves = gridDim.x * 4;
  int half = lane & 1;
  int sub = lane >> 1;  // 0..31
  f32x16 s2c, t2c, w0, w1;
#pragma unroll
  for (int i = 0; i < 16; ++i) {
    int c = half * 16 + i;
    s2c[i] = s2[c]; t2c[i] = t2[c];
    w0[i] = Wm3f[c * 2 + 0]; w1[i] = Wm3f[c * 2 + 1];
  }
  float bb0 = bm3f[0], bb1 = bm3f[1];
  const int ntiles = NE / 32;
#pragma unroll 2
  for (int t = wave; t < ntiles; t += nwaves) {
    int e = t * 32 + sub;
    const bf16x8* pa = (const bf16x8*)(a2s + (size_t)e * 32 + half * 16);
    bf16x8 v0 = pa[0], v1 = pa[1];
    float o0 = 0.f, o1 = 0.f;
#pragma unroll
    for (int i = 0; i < 8; ++i) {
      float z = (float)v0[i] * s2c[i] + t2c[i];
      o0 += z * w0[i]; o1 += z * w1[i];
      float z2 = (float)v1[i] * s2c[8 + i] + t2c[8 + i];
      o0 += z2 * w0[8 + i]; o1 += z2 * w1[8 + i];
    }
    o0 += __shfl_xor(o0, 1);
    o1 += __shfl_xor(o1, 1);
    if (half == 0) {
      o0 += bb0; o1 += bb1;
      if (sizeof(OT) == 2) {
        bf16_t p[2] = {(bf16_t)o0, (bf16_t)o1};
        unsigned pw;
        memcpy(&pw, p, 4);
        ((unsigned*)out)[e] = pw;
      } else {
        f32x2 pw = {o0, o1};
        ((f32x2*)out)[e] = pw;
      }
    }
  }
}

// ============ pass 3 tier C: recompute a2 and reduce -> out ============
template <typename OT>
__global__ __launch_bounds__(256) void k_out_recomp(const int* __restrict__ eic,
                                                    const bf16_t* __restrict__ u,
                                                    const bf16_t* __restrict__ v,
                                                    const float* __restrict__ bm1f,
                                                    const float* __restrict__ s1, const float* __restrict__ t1,
                                                    const float* __restrict__ Wm2f,
                                                    const float* __restrict__ bm2f,
                                                    const float* __restrict__ s2, const float* __restrict__ t2,
                                                    const float* __restrict__ Wm3f,
                                                    const float* __restrict__ bm3f,
                                                    OT* __restrict__ out,
                                                    const int* __restrict__ flags) {
  if (flags[0] != (int)(sizeof(OT) == 2)) return;
  int lane = threadIdx.x & 63;
  int wave = blockIdx.x * 4 + (threadIdx.x >> 6);
  int nwaves = gridDim.x * 4;
  int n = lane & 15, q = lane >> 4;
  f32x16 bk, s1k, t1k;
#pragma unroll
  for (int j = 0; j < 8; ++j) {
    bk[j] = bm1f[q * 8 + j];       bk[8 + j] = bm1f[32 + q * 8 + j];
    s1k[j] = s1[q * 8 + j];        s1k[8 + j] = s1[32 + q * 8 + j];
    t1k[j] = t1[q * 8 + j];        t1k[8 + j] = t1[32 + q * 8 + j];
  }
  bf16x8 b2h00, b2h01, b2h10, b2h11;
#pragma unroll
  for (int j = 0; j < 8; ++j) {
    b2h00[j] = (bf16_t)Wm2f[(q * 8 + j) * 32 + 0 * 16 + n];
    b2h01[j] = (bf16_t)Wm2f[(q * 8 + j) * 32 + 1 * 16 + n];
    b2h10[j] = (bf16_t)Wm2f[(32 + q * 8 + j) * 32 + 0 * 16 + n];
    b2h11[j] = (bf16_t)Wm2f[(32 + q * 8 + j) * 32 + 1 * 16 + n];
  }
  float bias20 = bm2f[n], bias21 = bm2f[16 + n];
  float s2c0 = s2[n], t2c0 = t2[n], s2c1 = s2[16 + n], t2c1 = t2[16 + n];
  float w3a0 = Wm3f[n * 2 + 0], w3a1 = Wm3f[n * 2 + 1];
  float w3b0 = Wm3f[(16 + n) * 2 + 0], w3b1 = Wm3f[(16 + n) * 2 + 1];
  float bb0 = bm3f[0], bb1 = bm3f[1];

  for (int t = wave; t < NE / 16; t += nwaves) {
    int e = t * 16 + n;
    int src = eic[e], dst = eic[NE + e];
    const bf16x8* pu = (const bf16x8*)(u + src * 64);
    const bf16x8* pv = (const bf16x8*)(v + dst * 64);
    bf16x8 ua = pu[q], ub = pu[4 + q], va = pv[q], vb = pv[4 + q];
    f32x16 a1k;
#pragma unroll
    for (int j = 0; j < 8; ++j) {
      a1k[j] = fmaxf((float)ua[j] + (float)va[j] + bk[j], 0.f);
      a1k[8 + j] = fmaxf((float)ub[j] + (float)vb[j] + bk[8 + j], 0.f);
    }
    f32x16 z = a1k * s1k + t1k;
    bf16x8 g0h, g0l, g1h, g1l;
#pragma unroll
    for (int j = 0; j < 8; ++j) {
      float z0 = z[j], z1 = z[8 + j];
      bf16_t h0 = (bf16_t)z0, h1 = (bf16_t)z1;
      g0h[j] = h0; g0l[j] = (bf16_t)(z0 - (float)h0);
      g1h[j] = h1; g1l[j] = (bf16_t)(z1 - (float)h1);
    }
    f32x4 c0 = {0.f, 0.f, 0.f, 0.f}, c1 = {0.f, 0.f, 0.f, 0.f};
    c0 = __builtin_amdgcn_mfma_f32_16x16x32_bf16(g0h, b2h00, c0, 0, 0, 0);
    c0 = __builtin_amdgcn_mfma_f32_16x16x32_bf16(g0l, b2h00, c0, 0, 0, 0);
    c0 = __builtin_amdgcn_mfma_f32_16x16x32_bf16(g1h, b2h10, c0, 0, 0, 0);
    c0 = __builtin_amdgcn_mfma_f32_16x16x32_bf16(g1l, b2h10, c0, 0, 0, 0);
    c1 = __builtin_amdgcn_mfma_f32_16x16x32_bf16(g0h, b2h01, c1, 0, 0, 0);
    c1 = __builtin_amdgcn_mfma_f32_16x16x32_bf16(g0l, b2h01, c1, 0, 0, 0);
    c1 = __builtin_amdgcn_mfma_f32_16x16x32_bf16(g1h, b2h11, c1, 0, 0, 0);
    c1 = __builtin_amdgcn_mfma_f32_16x16x32_bf16(g1l, b2h11, c1, 0, 0, 0);
#pragma unroll
    for (int r = 0; r < 4; ++r) {
      float z0 = fmaxf(c0[r] + bias20, 0.f) * s2c0 + t2c0;
      float z1 = fmaxf(c1[r] + bias21, 0.f) * s2c1 + t2c1;
      float o0 = z0 * w3a0 + z1 * w3b0;
      float o1 = z0 * w3a1 + z1 * w3b1;
      o0 += __shfl_xor(o0, 1); o0 += __shfl_xor(o0, 2);
      o0 += __shfl_xor(o0, 4); o0 += __shfl_xor(o0, 8);
      o1 += __shfl_xor(o1, 1); o1 += __shfl_xor(o1, 2);
      o1 += __shfl_xor(o1, 4); o1 += __shfl_xor(o1, 8);
      if (n == 0) {
        int eo = t * 16 + q * 4 + r;
        o0 += bb0; o1 += bb1;
        if (sizeof(OT) == 2) {
          bf16_t p[2] = {(bf16_t)o0, (bf16_t)o1};
          unsigned pw;
          memcpy(&pw, p, 4);
          ((unsigned*)out)[eo] = pw;
        } else {
          f32x2 pw = {o0, o1};
          ((f32x2*)out)[eo] = pw;
        }
      }
    }
  }
}

// ---------------- host ----------------
extern "C" void kernel_launch(void* const* d_in, const int* in_sizes, int n_in,
                              void* d_out, int out_size, void* d_ws, size_t ws_size,
                              hipStream_t stream) {
  (void)n_in; (void)in_sizes; (void)out_size;

  char* ws = (char*)d_ws;
  size_t off = 0;
  auto alloc = [&](size_t bytes) {
    size_t r = off;
    off = (off + bytes + 255) & ~(size_t)255;
    return r;
  };
  float* dinv  = (float*)(ws + alloc((size_t)NN * 4));
  float* hs    = (float*)(ws + alloc((size_t)NN * HID * 4));
  float* agg   = (float*)(ws + alloc((size_t)NN * HID * 4));  // hs3
  int*   eic   = (int*)(ws + alloc((size_t)2 * NE * 4));
  float* stats = (float*)(ws + alloc(192 * 4));
  float* sum1 = stats, *sq1 = stats + 64, *sum2 = stats + 128, *sq2 = stats + 160;
  int*   flags = (int*)(ws + alloc(256));
  float* s1arr = (float*)(ws + alloc(64 * 4));
  float* t1arr = (float*)(ws + alloc(64 * 4));
  float* s2arr = (float*)(ws + alloc(32 * 4));
  float* t2arr = (float*)(ws + alloc(32 * 4));
  // dst-CSR (GCN gather)
  int* cnt     = (int*)(ws + alloc((size_t)NN * 4));
  int* rowptr  = (int*)(ws + alloc((size_t)NN * 4));
  int* cursor  = (int*)(ws + alloc((size_t)NN * 4));
  int* bsum    = (int*)(ws + alloc(512 * 4));
  int* btop    = (int*)(ws + alloc(512 * 4));
  int* csr_src = (int*)(ws + alloc((size_t)NE * 4));
  // node-level MLP factors + 3-dim staging
  bf16_t* u    = (bf16_t*)(ws + alloc((size_t)NN * HID * 2));
  bf16_t* v    = (bf16_t*)(ws + alloc((size_t)NN * HID * 2));
  f32x4* xs4   = (f32x4*)(ws + alloc((size_t)NN * 16));
  f32x4* agg3  = (f32x4*)(ws + alloc((size_t)NN * 16));

  // canonical f32 input block
  static const int flens[17] = {NN * 3, 3 * 64, 64, 64 * 64, 64, 64 * 64, 64,
                                128 * 64, 64, 64, 64, 64 * 32, 32, 32, 32, 32 * 2, 2};
  FPtrs fp;
  int total_f = 0;
  {
    int fi = 0;
    for (int i = 0; i < 18; ++i) {
      if (i == 1) continue;
      fp.p[fi] = d_in[i];
      fp.len[fi] = flens[fi];
      fp.ofs[fi] = total_f;
      total_f += flens[fi];
      ++fi;
    }
  }
  float* canon = (float*)(ws + alloc((size_t)total_f * 4));
  size_t a2_off = alloc((size_t)NE * 32 * 2);
  bf16_t* a2s = (bf16_t*)(ws + a2_off);
  bool tierB = (a2_off + (size_t)NE * 32 * 2) <= ws_size;

  const float* xf   = canon + fp.ofs[0];
  const float* W1f  = canon + fp.ofs[1];
  const float* b1f  = canon + fp.ofs[2];
  const float* W2f  = canon + fp.ofs[3];
  const float* b2f  = canon + fp.ofs[4];
  const float* W3f  = canon + fp.ofs[5];
  const float* b3f  = canon + fp.ofs[6];
  const float* Wm1f = canon + fp.ofs[7];
  const float* bm1f = canon + fp.ofs[8];
  const float* g1f  = canon + fp.ofs[9];
  const float* be1f = canon + fp.ofs[10];
  const float* Wm2f = canon + fp.ofs[11];
  const float* bm2f = canon + fp.ofs[12];
  const float* g2f  = canon + fp.ofs[13];
  const float* be2f = canon + fp.ofs[14];
  const float* Wm3f = canon + fp.ofs[15];
  const float* bm3f = canon + fp.ofs[16];

  const int nscanb = (NN + 255) / 256;  // 391

  // 0) detect dtypes, canonicalize
  k_detect<<<1, 64, 0, stream>>>((const unsigned*)d_in[0], (const int*)d_in[1], flags);
  k_cvt_idx<int><<<1600, 256, 0, stream>>>((const int*)d_in[1], eic, flags);
  k_cvt_idx<long long><<<1600, 256, 0, stream>>>((const long long*)d_in[1], eic, flags);
  k_cvt_f<float><<<640, 256, 0, stream>>>(fp, canon, flags, total_f);
  k_cvt_f<bf16_t><<<640, 256, 0, stream>>>(fp, canon, flags, total_f);

  // 1) CSR build + dinv + stats zero
  k_zero4<<<128, 256, 0, stream>>>((f32x4*)cnt, NN / 4);
  k_zero4<<<1, 64, 0, stream>>>((f32x4*)stats, 48);
  k_count<<<1600, 256, 0, stream>>>(eic + NE, cnt);
  k_dinv<<<(NN + 255) / 256, 256, 0, stream>>>(cnt, dinv);
  k_scan1<<<nscanb, 256, 0, stream>>>(cnt, rowptr, bsum, NN);
  k_scan2<<<1, 512, 0, stream>>>(bsum, btop, nscanb);
  k_scan3<<<nscanb, 256, 0, stream>>>(rowptr, btop, cursor, NN);
  k_fill<<<1600, 256, 0, stream>>>(eic, cursor, csr_src);

  // ---- GCN layer 1 (3-dim aggregation; aggregation commutes with @W1) ----
  k_xs<<<(NN + 255) / 256, 256, 0, stream>>>(xf, dinv, xs4);
  k_g1<<<2048, 256, 0, stream>>>(rowptr, cnt, csr_src, xs4, dinv, agg3);
  k_f1<<<1024, 512, 0, stream>>>(agg3, W1f, b1f, W2f, dinv, hs);  // hs2

  // ---- GCN layer 2 (gather + fused @W3*dinv; 8-wave blocks for full occupancy) ----
  k_g2<<<1024, 512, 0, stream>>>(rowptr, cnt, csr_src, hs, dinv, b2f, W3f, agg);  // hs3

  // ---- GCN layer 3 (gather + fused @Wm1 halves -> u,v; 8-wave blocks) ----
  k_g3<<<1024, 512, 0, stream>>>(rowptr, cnt, csr_src, agg, dinv, b3f, Wm1f, u, v);

  // ---- edge MLP ----
  k_e1<<<2048, 256, 0, stream>>>(eic, u, v, bm1f, sum1, sq1);
  k_bnconst<<<1, 64, 0, stream>>>(sum1, sq1, g1f, be1f, s1arr, t1arr, 64);
  if (tierB) {
    k_e2<true><<<2048, 256, 0, stream>>>(eic, u, v, bm1f, s1arr, t1arr, Wm2f, bm2f, a2s,
                                         sum2, sq2);
    k_bnconst<<<1, 64, 0, stream>>>(sum2, sq2, g2f, be2f, s2arr, t2arr, 32);
    k_out_stream<float><<<2048, 256, 0, stream>>>(a2s, s2arr, t2arr, Wm3f, bm3f,
                                                  (float*)d_out, flags);
    k_out_stream<bf16_t><<<2048, 256, 0, stream>>>(a2s, s2arr, t2arr, Wm3f, bm3f,
                                                   (bf16_t*)d_out, flags);
  } else {
    k_e2<false><<<2048, 256, 0, stream>>>(eic, u, v, bm1f, s1arr, t1arr, Wm2f, bm2f, a2s,
                                          sum2, sq2);
    k_bnconst<<<1, 64, 0, stream>>>(sum2, sq2, g2f, be2f, s2arr, t2arr, 32);
    k_out_recomp<float><<<2048, 256, 0, stream>>>(eic, u, v, bm1f, s1arr, t1arr, Wm2f,
                                                  bm2f, s2arr, t2arr, Wm3f, bm3f,
                                                  (float*)d_out, flags);
    k_out_recomp<bf16_t><<<2048, 256, 0, stream>>>(eic, u, v, bm1f, s1arr, t1arr, Wm2f,
                                                   bm2f, s2arr, t2arr, Wm3f, bm3f,
                                                   (bf16_t*)d_out, flags);
  }
}

// Round 13
// 699.506 us; speedup vs baseline: 3.6844x; 1.1160x over previous
//
#include <hip/hip_runtime.h>
#include <hip/hip_bf16.h>
#include <cstdint>
#include <cstring>

#define NN 100000
#define NE 1600000
#define HID 64
#define EPS 1e-5f
#define NB1 128
#define BSZ 782  // ceil(NN/NB1); 128*782 = 100096 >= NN

typedef __bf16 bf16_t;
typedef __attribute__((ext_vector_type(8))) __bf16 bf16x8;
typedef __attribute__((ext_vector_type(4))) float f32x4;
typedef __attribute__((ext_vector_type(2))) float f32x2;
typedef __attribute__((ext_vector_type(16))) float f32x16;

#define LDS_FENCE() asm volatile("s_waitcnt lgkmcnt(0)" ::: "memory")

// ---------------- dtype detectors ----------------
__global__ void k_detect(const unsigned* __restrict__ xw, const int* __restrict__ eiw,
                         int* __restrict__ flags) {
  int lane = threadIdx.x;  // 64
  unsigned u = xw[lane];
  unsigned lo = u & 0xFFFFu;
  unsigned e = (lo >> 7) & 0xFFu;
  bool bf_ok = (lo == 0u) || (e >= 0x50u && e <= 0x8Fu);
  unsigned long long b1 = __ballot(bf_ok);
  int v = eiw[2 * lane + 1];
  unsigned long long b2 = __ballot(v == 0);
  if (lane == 0) {
    flags[0] = (b1 == ~0ull) ? 1 : 0;
    flags[1] = (b2 == ~0ull) ? 1 : 0;
  }
}

// ---------------- input canonicalization ----------------
struct FPtrs {
  const void* p[17];
  int len[17];
  int ofs[17];
};

template <typename FT>
__global__ void k_cvt_f(FPtrs fp, float* __restrict__ canon, const int* __restrict__ flags,
                        int total) {
  if (flags[0] != (int)(sizeof(FT) == 2)) return;
  int i = blockIdx.x * blockDim.x + threadIdx.x;
  int stride = gridDim.x * blockDim.x;
  for (int t = i; t < total; t += stride) {
    int seg = 0;
    while (seg < 16 && t >= fp.ofs[seg] + fp.len[seg]) ++seg;
    canon[t] = (float)((const FT*)fp.p[seg])[t - fp.ofs[seg]];
  }
}

template <typename IT>
__global__ void k_cvt_idx(const IT* __restrict__ ei, int* __restrict__ eic,
                          const int* __restrict__ flags) {
  if (flags[1] != (int)(sizeof(IT) == 8)) return;
  int i = blockIdx.x * blockDim.x + threadIdx.x;
  int stride = gridDim.x * blockDim.x;
  for (int t = i; t < 2 * NE; t += stride) eic[t] = (int)ei[t];
}

// ---------------- utility: zero fill ----------------
__global__ void k_zero4(f32x4* __restrict__ p, int n4) {
  int i = blockIdx.x * blockDim.x + threadIdx.x;
  int stride = gridDim.x * blockDim.x;
  f32x4 z = {0.f, 0.f, 0.f, 0.f};
  for (int t = i; t < n4; t += stride) p[t] = z;
}

// ---------------- CSR build: bucketed two-phase (full-line writes) ----------------
// counts: per-node cnt (atomics, spread) + per-bucket bcnt (LDS hist -> 128 atomics/block)
__global__ __launch_bounds__(256) void k_cnt2(const int* __restrict__ dstp,
                                              int* __restrict__ cnt, int* __restrict__ bcnt) {
  __shared__ int lh[NB1];
  int tid = threadIdx.x;
  if (tid < NB1) lh[tid] = 0;
  __syncthreads();
  const int per = NE / 200;  // 8000, grid=200 exact
  int e0 = blockIdx.x * per;
  for (int k = tid; k < per; k += 256) {
    int dst = dstp[e0 + k];
    atomicAdd(&cnt[dst], 1);
    atomicAdd(&lh[dst / BSZ], 1);
  }
  __syncthreads();
  if (tid < NB1) atomicAdd(&bcnt[tid], lh[tid]);
}

__global__ void k_dinv(const int* __restrict__ cnt, float* __restrict__ d) {
  int n = blockIdx.x * blockDim.x + threadIdx.x;
  if (n < NN) d[n] = rsqrtf((float)cnt[n] + 1.0f);  // self-loop
}

__global__ void k_scan1(const int* __restrict__ cnt, int* __restrict__ rowptr,
                        int* __restrict__ bsum, int nvals) {
  __shared__ int tmp[256];
  int gid = blockIdx.x * 256 + threadIdx.x;
  int v = (gid < nvals) ? cnt[gid] : 0;
  tmp[threadIdx.x] = v;
  __syncthreads();
  for (int s = 1; s < 256; s <<= 1) {
    int add = (threadIdx.x >= s) ? tmp[threadIdx.x - s] : 0;
    __syncthreads();
    tmp[threadIdx.x] += add;
    __syncthreads();
  }
  if (gid < nvals) rowptr[gid] = tmp[threadIdx.x] - v;
  if (threadIdx.x == 255) bsum[blockIdx.x] = tmp[255];
}

__global__ void k_scan2(int* __restrict__ bsum, int* __restrict__ btop, int nblocks) {
  __shared__ int tmp[512];
  int v = (threadIdx.x < nblocks) ? bsum[threadIdx.x] : 0;
  tmp[threadIdx.x] = v;
  __syncthreads();
  for (int s = 1; s < 512; s <<= 1) {
    int add = (threadIdx.x >= s) ? tmp[threadIdx.x - s] : 0;
    __syncthreads();
    tmp[threadIdx.x] += add;
    __syncthreads();
  }
  if (threadIdx.x < nblocks) btop[threadIdx.x] = tmp[threadIdx.x] - v;
}

__global__ void k_scan3(int* __restrict__ rowptr, const int* __restrict__ btop, int nvals) {
  int gid = blockIdx.x * 256 + threadIdx.x;
  if (gid < nvals) rowptr[gid] += btop[blockIdx.x];
}

// scan of 128 bucket counts -> bptr (exclusive), bcur copy
__global__ void k_scanb(const int* __restrict__ bcnt, int* __restrict__ bptr,
                        int* __restrict__ bcur) {
  __shared__ int tmp[NB1];
  int j = threadIdx.x;  // 128
  int v = bcnt[j];
  tmp[j] = v;
  __syncthreads();
  for (int s = 1; s < NB1; s <<= 1) {
    int a = (j >= s) ? tmp[j - s] : 0;
    __syncthreads();
    tmp[j] += a;
    __syncthreads();
  }
  bptr[j] = tmp[j] - v;
  bcur[j] = tmp[j] - v;
}

// phase 1: bin 2048 edges per block by coarse bucket in LDS, write bin-contiguous runs
__global__ __launch_bounds__(256) void k_p1(const int* __restrict__ eic,
                                            int* __restrict__ bcur,
                                            long long* __restrict__ staging) {
  __shared__ long long buf[2048];
  __shared__ int tgt[2048];
  __shared__ int hist[NB1], lbase[NB1], gbase[NB1];
  int tid = threadIdx.x;
  int e0 = blockIdx.x * 2048;
  int cntE = NE - e0;
  if (cntE > 2048) cntE = 2048;
  if (tid < NB1) hist[tid] = 0;
  __syncthreads();
  int slotk[8], bk[8];
  long long pk[8];
#pragma unroll
  for (int k = 0; k < 8; ++k) {
    int i = k * 256 + tid;
    bk[k] = -1;
    if (i < cntE) {
      int e = e0 + i;
      int src = eic[e], dst = eic[NE + e];
      bk[k] = dst / BSZ;
      pk[k] = ((long long)(unsigned)src) | (((long long)(unsigned)dst) << 32);
      slotk[k] = atomicAdd(&hist[bk[k]], 1);
    }
  }
  __syncthreads();
  if (tid < NB1) lbase[tid] = hist[tid];
  __syncthreads();
  for (int s = 1; s < NB1; s <<= 1) {
    int a = 0;
    if (tid < NB1 && tid >= s) a = lbase[tid - s];
    __syncthreads();
    if (tid < NB1) lbase[tid] += a;
    __syncthreads();
  }
  if (tid < NB1) {
    int exc = lbase[tid] - hist[tid];
    lbase[tid] = exc;
    gbase[tid] = (hist[tid] > 0) ? atomicAdd(&bcur[tid], hist[tid]) : 0;
  }
  __syncthreads();
#pragma unroll
  for (int k = 0; k < 8; ++k) {
    if (bk[k] >= 0) {
      int idx = lbase[bk[k]] + slotk[k];
      buf[idx] = pk[k];
      tgt[idx] = gbase[bk[k]] + slotk[k];
    }
  }
  __syncthreads();
  for (int i = tid; i < cntE; i += 256) staging[tgt[i]] = buf[i];
}

// phase 2: per-bucket exact CSR via LDS cursors; contiguous csr region per block
__global__ __launch_bounds__(256) void k_p2(const long long* __restrict__ staging,
                                            const int* __restrict__ bptr,
                                            const int* __restrict__ bcnt,
                                            const int* __restrict__ rowptr,
                                            int* __restrict__ csr_src) {
  __shared__ int lcur[BSZ];
  int b = blockIdx.x;  // 128
  int nb0 = b * BSZ;
  int nN = NN - nb0;
  if (nN > BSZ) nN = BSZ;
  int tid = threadIdx.x;
  for (int i = tid; i < nN; i += 256) lcur[i] = rowptr[nb0 + i];
  __syncthreads();
  int beg = bptr[b], cntE = bcnt[b];
  for (int k = tid; k < cntE; k += 256) {
    long long p = staging[beg + k];
    int src = (int)(p & 0xffffffffLL);
    int dst = (int)(p >> 32);
    int pos = atomicAdd(&lcur[dst - nb0], 1);
    csr_src[pos] = src;
  }
}

// ---------------- xs = x * dinv (float4-padded) ----------------
__global__ void k_xs(const float* __restrict__ x, const float* __restrict__ dinv,
                     f32x4* __restrict__ xs4) {
  int n = blockIdx.x * blockDim.x + threadIdx.x;
  if (n >= NN) return;
  float d = dinv[n];
  f32x4 r = {x[n * 3 + 0] * d, x[n * 3 + 1] * d, x[n * 3 + 2] * d, 0.f};
  xs4[n] = r;
}

// ---------------- g1: 3-dim aggregate of xs -> agg3 = (sum + self)*dinv ----------------
__global__ __launch_bounds__(256) void k_g1(const int* __restrict__ rowptr,
                                            const int* __restrict__ cnt,
                                            const int* __restrict__ csr_src,
                                            const f32x4* __restrict__ xs4,
                                            const float* __restrict__ dinv,
                                            f32x4* __restrict__ agg3) {
  int wid = (blockIdx.x * blockDim.x + threadIdx.x) >> 6;
  int nw = (gridDim.x * blockDim.x) >> 6;
  int lane = threadIdx.x & 63;
  int comp = lane & 3, slot = lane >> 2;  // 16 slots x 4 comps
  for (int n = wid; n < NN; n += nw) {
    int beg = rowptr[n], c = cnt[n];
    float acc = 0.f;
    for (int k = slot; k < c; k += 16) {
      int src = csr_src[beg + k];
      acc += ((const float*)(xs4 + src))[comp];
    }
    acc += __shfl_xor(acc, 4); acc += __shfl_xor(acc, 8);
    acc += __shfl_xor(acc, 16); acc += __shfl_xor(acc, 32);
    if (lane < 4) {
      float self = ((const float*)(xs4 + n))[comp];
      ((float*)(agg3 + n))[comp] = (acc + self) * dinv[n];
    }
  }
}

// ---------------- f1: h1 = relu(agg3@W1+b1); hs2 = (h1@W2)*dinv  (512 thr, 8 waves) ----------------
__global__ __launch_bounds__(512) void k_f1(const f32x4* __restrict__ agg3,
                                            const float* __restrict__ W1f,
                                            const float* __restrict__ b1f,
                                            const float* __restrict__ W2f,
                                            const float* __restrict__ dinv,
                                            float* __restrict__ hs) {
  __shared__ float W1l[192];
  __shared__ float b1l[64];
  __shared__ float W2l[64 * 64];
  __shared__ float hrow[8][64];
  int tid = threadIdx.x;
  if (tid < 192) W1l[tid] = W1f[tid];
  if (tid < 64) b1l[tid] = b1f[tid];
  for (int i = tid; i < 64 * 64; i += 512) W2l[i] = W2f[i];
  __syncthreads();
  int w = tid >> 6, j = tid & 63;
  for (int nb = blockIdx.x * 8 + w; nb < NN; nb += gridDim.x * 8) {
    f32x4 a = agg3[nb];
    float h = fmaxf(a[0] * W1l[j] + a[1] * W1l[64 + j] + a[2] * W1l[128 + j] + b1l[j], 0.f);
    hrow[w][j] = h;
    LDS_FENCE();
    float acc = 0.f;
#pragma unroll 8
    for (int k = 0; k < 64; ++k) acc += hrow[w][k] * W2l[k * 64 + j];
    hs[nb * 64 + j] = acc * dinv[nb];
  }
}

// ---------------- g2: gather hs2 -> h2 = relu((sum+self)*dinv+b2); hs3 = (h2@W3)*dinv ----------------
__global__ __launch_bounds__(512) void k_g2(const int* __restrict__ rowptr,
                                            const int* __restrict__ cnt,
                                            const int* __restrict__ csr_src,
                                            const float* __restrict__ hs,
                                            const float* __restrict__ dinv,
                                            const float* __restrict__ b2f,
                                            const float* __restrict__ W3f,
                                            float* __restrict__ hs3) {
  __shared__ float W3l[64 * 64];
  __shared__ float hrow[8][64];
  int tid = threadIdx.x;
  for (int i = tid; i < 64 * 64; i += 512) W3l[i] = W3f[i];
  __syncthreads();
  int w = tid >> 6, j = tid & 63;
  float rb = b2f[j];
  for (int n = blockIdx.x * 8 + w; n < NN; n += gridDim.x * 8) {
    int beg = rowptr[n], c = cnt[n];
    float acc = hs[n * 64 + j];  // self
    int k = 0;
    for (; k + 8 <= c; k += 8) {
      int s0 = csr_src[beg + k + 0], s1 = csr_src[beg + k + 1];
      int s2 = csr_src[beg + k + 2], s3 = csr_src[beg + k + 3];
      int s4 = csr_src[beg + k + 4], s5 = csr_src[beg + k + 5];
      int s6 = csr_src[beg + k + 6], s7 = csr_src[beg + k + 7];
      float v0 = hs[s0 * 64 + j], v1 = hs[s1 * 64 + j];
      float v2 = hs[s2 * 64 + j], v3 = hs[s3 * 64 + j];
      float v4 = hs[s4 * 64 + j], v5 = hs[s5 * 64 + j];
      float v6 = hs[s6 * 64 + j], v7 = hs[s7 * 64 + j];
      acc += ((v0 + v1) + (v2 + v3)) + ((v4 + v5) + (v6 + v7));
    }
    for (; k < c; ++k) acc += hs[csr_src[beg + k] * 64 + j];
    float h2 = fmaxf(acc * dinv[n] + rb, 0.f);
    hrow[w][j] = h2;
    LDS_FENCE();
    float s = 0.f;
#pragma unroll 8
    for (int kk = 0; kk < 64; ++kk) s += hrow[w][kk] * W3l[kk * 64 + j];
    hs3[n * 64 + j] = s * dinv[n];
  }
}

// ---------------- g3: gather hs3 -> h3; u,v = h3 @ Wm1 halves  (512 thr, 8 waves) ----------------
__global__ __launch_bounds__(512) void k_g3(const int* __restrict__ rowptr,
                                            const int* __restrict__ cnt,
                                            const int* __restrict__ csr_src,
                                            const float* __restrict__ hs3,
                                            const float* __restrict__ dinv,
                                            const float* __restrict__ b3f,
                                            const float* __restrict__ Wm1f,
                                            bf16_t* __restrict__ u, bf16_t* __restrict__ v) {
  __shared__ float Wt[64 * 64];
  __shared__ float Wb[64 * 64];
  __shared__ float hrow[8][64];
  int tid = threadIdx.x;
  for (int i = tid; i < 64 * 64; i += 512) {
    Wt[i] = Wm1f[i];
    Wb[i] = Wm1f[4096 + i];
  }
  __syncthreads();
  int w = tid >> 6, j = tid & 63;
  float rb = b3f[j];
  for (int n = blockIdx.x * 8 + w; n < NN; n += gridDim.x * 8) {
    int beg = rowptr[n], c = cnt[n];
    float acc = hs3[n * 64 + j];  // self
    int k = 0;
    for (; k + 8 <= c; k += 8) {
      int s0 = csr_src[beg + k + 0], s1 = csr_src[beg + k + 1];
      int s2 = csr_src[beg + k + 2], s3 = csr_src[beg + k + 3];
      int s4 = csr_src[beg + k + 4], s5 = csr_src[beg + k + 5];
      int s6 = csr_src[beg + k + 6], s7 = csr_src[beg + k + 7];
      float v0 = hs3[s0 * 64 + j], v1 = hs3[s1 * 64 + j];
      float v2 = hs3[s2 * 64 + j], v3 = hs3[s3 * 64 + j];
      float v4 = hs3[s4 * 64 + j], v5 = hs3[s5 * 64 + j];
      float v6 = hs3[s6 * 64 + j], v7 = hs3[s7 * 64 + j];
      acc += ((v0 + v1) + (v2 + v3)) + ((v4 + v5) + (v6 + v7));
    }
    for (; k < c; ++k) acc += hs3[csr_src[beg + k] * 64 + j];
    float h3 = acc * dinv[n] + rb;  // no relu
    hrow[w][j] = h3;
    LDS_FENCE();
    float au = 0.f, av = 0.f;
#pragma unroll 8
    for (int kk = 0; kk < 64; ++kk) {
      float hv = hrow[w][kk];
      au += hv * Wt[kk * 64 + j];
      av += hv * Wb[kk * 64 + j];
    }
    u[n * 64 + j] = (bf16_t)au;
    v[n * 64 + j] = (bf16_t)av;
  }
}

// ============ pass 1: BN1 stats of a1 = relu(u[src]+v[dst]+bm1) ============
__global__ __launch_bounds__(256) void k_e1(const int* __restrict__ eic,
                                            const bf16_t* __restrict__ u,
                                            const bf16_t* __restrict__ v,
                                            const float* __restrict__ bm1f,
                                            float* __restrict__ sum1,
                                            float* __restrict__ sq1) {
  __shared__ float reds[16][16];
  __shared__ float redq[16][16];
  int lane = threadIdx.x & 63;
  int wv = threadIdx.x >> 6;
  int wave = blockIdx.x * 4 + wv;
  int nwaves = gridDim.x * 4;
  int n = lane & 15, q = lane >> 4;
  f32x16 bk;
#pragma unroll
  for (int j = 0; j < 8; ++j) {
    bk[j] = bm1f[q * 8 + j];
    bk[8 + j] = bm1f[32 + q * 8 + j];
  }
  f32x16 accs = {};
  f32x16 accq = {};
#pragma unroll 2
  for (int t = wave; t < NE / 16; t += nwaves) {
    int e = t * 16 + n;
    int src = eic[e], dst = eic[NE + e];
    const bf16x8* pu = (const bf16x8*)(u + src * 64);
    const bf16x8* pv = (const bf16x8*)(v + dst * 64);
    bf16x8 ua = pu[q], ub = pu[4 + q], va = pv[q], vb = pv[4 + q];
    f32x16 a1k;
#pragma unroll
    for (int j = 0; j < 8; ++j) {
      a1k[j] = fmaxf((float)ua[j] + (float)va[j] + bk[j], 0.f);
      a1k[8 + j] = fmaxf((float)ub[j] + (float)vb[j] + bk[8 + j], 0.f);
    }
    accs += a1k;
    accq += a1k * a1k;
  }
#pragma unroll
  for (int j = 0; j < 16; ++j) {
    float s = accs[j], qq = accq[j];
    s += __shfl_xor(s, 1); s += __shfl_xor(s, 2);
    s += __shfl_xor(s, 4); s += __shfl_xor(s, 8);
    qq += __shfl_xor(qq, 1); qq += __shfl_xor(qq, 2);
    qq += __shfl_xor(qq, 4); qq += __shfl_xor(qq, 8);
    if (n == 0) {
      reds[wv * 4 + q][j] = s;
      redq[wv * 4 + q][j] = qq;
    }
  }
  __syncthreads();
  int tid = threadIdx.x;
  if (tid < 64) {
    int jq = (tid & 31) >> 3, elem = (tid >> 5) * 8 + (tid & 7);
    float s = reds[jq][elem] + reds[4 + jq][elem] + reds[8 + jq][elem] + reds[12 + jq][elem];
    float qq = redq[jq][elem] + redq[4 + jq][elem] + redq[8 + jq][elem] + redq[12 + jq][elem];
    unsafeAtomicAdd(&sum1[tid], s);
    unsafeAtomicAdd(&sq1[tid], qq);
  }
}

// ---------------- BN affine constants ----------------
__global__ void k_bnconst(const float* __restrict__ sum, const float* __restrict__ sq,
                          const float* __restrict__ g, const float* __restrict__ be,
                          float* __restrict__ sarr, float* __restrict__ tarr, int ncol) {
  int j = threadIdx.x;
  if (j >= ncol) return;
  float mu = sum[j] / (float)NE;
  float var = fmaxf(sq[j] / (float)NE - mu * mu, 0.f);
  float s = g[j] * rsqrtf(var + EPS);
  sarr[j] = s;
  tarr[j] = be[j] - mu * s;
}

// ============ pass 2: BN2 stats of a2 (+ optional store of pre-BN a2) ============
template <bool STORE>
__global__ __launch_bounds__(256) void k_e2(const int* __restrict__ eic,
                                            const bf16_t* __restrict__ u,
                                            const bf16_t* __restrict__ v,
                                            const float* __restrict__ bm1f,
                                            const float* __restrict__ s1, const float* __restrict__ t1,
                                            const float* __restrict__ Wm2f,
                                            const float* __restrict__ bm2f,
                                            bf16_t* __restrict__ a2s,
                                            float* __restrict__ sum2,
                                            float* __restrict__ sq2) {
  __shared__ float red2[4][4][16];  // [wv][{s0,q0,s1,q1}][n]
  int lane = threadIdx.x & 63;
  int wv = threadIdx.x >> 6;
  int wave = blockIdx.x * 4 + wv;
  int nwaves = gridDim.x * 4;
  int n = lane & 15, q = lane >> 4;
  f32x16 bk, s1k, t1k;
#pragma unroll
  for (int j = 0; j < 8; ++j) {
    bk[j] = bm1f[q * 8 + j];       bk[8 + j] = bm1f[32 + q * 8 + j];
    s1k[j] = s1[q * 8 + j];        s1k[8 + j] = s1[32 + q * 8 + j];
    t1k[j] = t1[q * 8 + j];        t1k[8 + j] = t1[32 + q * 8 + j];
  }
  bf16x8 b2h00, b2h01, b2h10, b2h11;
#pragma unroll
  for (int j = 0; j < 8; ++j) {
    b2h00[j] = (bf16_t)Wm2f[(q * 8 + j) * 32 + 0 * 16 + n];
    b2h01[j] = (bf16_t)Wm2f[(q * 8 + j) * 32 + 1 * 16 + n];
    b2h10[j] = (bf16_t)Wm2f[(32 + q * 8 + j) * 32 + 0 * 16 + n];
    b2h11[j] = (bf16_t)Wm2f[(32 + q * 8 + j) * 32 + 1 * 16 + n];
  }
  float bias20 = bm2f[n], bias21 = bm2f[16 + n];
  float accs0 = 0.f, accs1 = 0.f, accq0 = 0.f, accq1 = 0.f;
  for (int t = wave; t < NE / 16; t += nwaves) {
    int e = t * 16 + n;
    int src = eic[e], dst = eic[NE + e];
    const bf16x8* pu = (const bf16x8*)(u + src * 64);
    const bf16x8* pv = (const bf16x8*)(v + dst * 64);
    bf16x8 ua = pu[q], ub = pu[4 + q], va = pv[q], vb = pv[4 + q];
    f32x16 a1k;
#pragma unroll
    for (int j = 0; j < 8; ++j) {
      a1k[j] = fmaxf((float)ua[j] + (float)va[j] + bk[j], 0.f);
      a1k[8 + j] = fmaxf((float)ub[j] + (float)vb[j] + bk[8 + j], 0.f);
    }
    f32x16 z = a1k * s1k + t1k;
    bf16x8 g0h, g0l, g1h, g1l;
#pragma unroll
    for (int j = 0; j < 8; ++j) {
      float z0 = z[j], z1 = z[8 + j];
      bf16_t h0 = (bf16_t)z0, h1 = (bf16_t)z1;
      g0h[j] = h0; g0l[j] = (bf16_t)(z0 - (float)h0);
      g1h[j] = h1; g1l[j] = (bf16_t)(z1 - (float)h1);
    }
    f32x4 c0 = {0.f, 0.f, 0.f, 0.f}, c1 = {0.f, 0.f, 0.f, 0.f};
    c0 = __builtin_amdgcn_mfma_f32_16x16x32_bf16(g0h, b2h00, c0, 0, 0, 0);
    c0 = __builtin_amdgcn_mfma_f32_16x16x32_bf16(g0l, b2h00, c0, 0, 0, 0);
    c0 = __builtin_amdgcn_mfma_f32_16x16x32_bf16(g1h, b2h10, c0, 0, 0, 0);
    c0 = __builtin_amdgcn_mfma_f32_16x16x32_bf16(g1l, b2h10, c0, 0, 0, 0);
    c1 = __builtin_amdgcn_mfma_f32_16x16x32_bf16(g0h, b2h01, c1, 0, 0, 0);
    c1 = __builtin_amdgcn_mfma_f32_16x16x32_bf16(g0l, b2h01, c1, 0, 0, 0);
    c1 = __builtin_amdgcn_mfma_f32_16x16x32_bf16(g1h, b2h11, c1, 0, 0, 0);
    c1 = __builtin_amdgcn_mfma_f32_16x16x32_bf16(g1l, b2h11, c1, 0, 0, 0);
#pragma unroll
    for (int r = 0; r < 4; ++r) {
      float v0 = fmaxf(c0[r] + bias20, 0.f);
      float v1 = fmaxf(c1[r] + bias21, 0.f);
      if (STORE) {
        a2s[(size_t)(t * 16 + q * 4 + r) * 32 + n] = (bf16_t)v0;
        a2s[(size_t)(t * 16 + q * 4 + r) * 32 + 16 + n] = (bf16_t)v1;
      }
      accs0 += v0; accq0 += v0 * v0;
      accs1 += v1; accq1 += v1 * v1;
    }
  }
  accs0 += __shfl_xor(accs0, 16); accs0 += __shfl_xor(accs0, 32);
  accq0 += __shfl_xor(accq0, 16); accq0 += __shfl_xor(accq0, 32);
  accs1 += __shfl_xor(accs1, 16); accs1 += __shfl_xor(accs1, 32);
  accq1 += __shfl_xor(accq1, 16); accq1 += __shfl_xor(accq1, 32);
  if (lane < 16) {
    red2[wv][0][lane] = accs0;
    red2[wv][1][lane] = accq0;
    red2[wv][2][lane] = accs1;
    red2[wv][3][lane] = accq1;
  }
  __syncthreads();
  int tid = threadIdx.x;
  if (tid < 32) {
    int which = tid >> 4, nn = tid & 15;
    float s = red2[0][which * 2][nn] + red2[1][which * 2][nn] + red2[2][which * 2][nn] +
              red2[3][which * 2][nn];
    float qq = red2[0][which * 2 + 1][nn] + red2[1][which * 2 + 1][nn] +
               red2[2][which * 2 + 1][nn] + red2[3][which * 2 + 1][nn];
    unsafeAtomicAdd(&sum2[tid], s);
    unsafeAtomicAdd(&sq2[tid], qq);
  }
}

// ============ pass 3 tier B: stream stored a2 (original order) -> out ============
template <typename OT>
__global__ __launch_bounds__(256) void k_out_stream(const bf16_t* __restrict__ a2s,
                                                    const float* __restrict__ s2,
                                                    const float* __restrict__ t2,
                                                    const float* __restrict__ Wm3f,
                                                    const float* __restrict__ bm3f,
                                                    OT* __restrict__ out,
                                                    const int* __restrict__ flags) {
  if (flags[0] != (int)(sizeof(OT) == 2)) return;
  int lane = threadIdx.x & 63;
  int wave = blockIdx.x * 4 + (threadIdx.x >> 6);
  int nwaves = gridDim.x * 4;
  int half = lane & 1;
  int sub = lane >> 1;  // 0..31
  f32x16 s2c, t2c, w0, w1;
#pragma unroll
  for (int i = 0; i < 16; ++i) {
    int c = half * 16 + i;
    s2c[i] = s2[c]; t2c[i] = t2[c];
    w0[i] = Wm3f[c * 2 + 0]; w1[i] = Wm3f[c * 2 + 1];
  }
  float bb0 = bm3f[0], bb1 = bm3f[1];
  const int ntiles = NE / 32;
#pragma unroll 2
  for (int t = wave; t < ntiles; t += nwaves) {
    int e = t * 32 + sub;
    const bf16x8* pa = (const bf16x8*)(a2s + (size_t)e * 32 + half * 16);
    bf16x8 v0 = pa[0], v1 = pa[1];
    float o0 = 0.f, o1 = 0.f;
#pragma unroll
    for (int i = 0; i < 8; ++i) {
      float z = (float)v0[i] * s2c[i] + t2c[i];
      o0 += z * w0[i]; o1 += z * w1[i];
      float z2 = (float)v1[i] * s2c[8 + i] + t2c[8 + i];
      o0 += z2 * w0[8 + i]; o1 += z2 * w1[8 + i];
    }
    o0 += __shfl_xor(o0, 1);
    o1 += __shfl_xor(o1, 1);
    if (half == 0) {
      o0 += bb0; o1 += bb1;
      if (sizeof(OT) == 2) {
        bf16_t p[2] = {(bf16_t)o0, (bf16_t)o1};
        unsigned pw;
        memcpy(&pw, p, 4);
        ((unsigned*)out)[e] = pw;
      } else {
        f32x2 pw = {o0, o1};
        ((f32x2*)out)[e] = pw;
      }
    }
  }
}

// ============ pass 3 tier C: recompute a2 and reduce -> out ============
template <typename OT>
__global__ __launch_bounds__(256) void k_out_recomp(const int* __restrict__ eic,
                                                    const bf16_t* __restrict__ u,
                                                    const bf16_t* __restrict__ v,
                                                    const float* __restrict__ bm1f,
                                                    const float* __restrict__ s1, const float* __restrict__ t1,
                                                    const float* __restrict__ Wm2f,
                                                    const float* __restrict__ bm2f,
                                                    const float* __restrict__ s2, const float* __restrict__ t2,
                                                    const float* __restrict__ Wm3f,
                                                    const float* __restrict__ bm3f,
                                                    OT* __restrict__ out,
                                                    const int* __restrict__ flags) {
  if (flags[0] != (int)(sizeof(OT) == 2)) return;
  int lane = threadIdx.x & 63;
  int wave = blockIdx.x * 4 + (threadIdx.x >> 6);
  int nwaves = gridDim.x * 4;
  int n = lane & 15, q = lane >> 4;
  f32x16 bk, s1k, t1k;
#pragma unroll
  for (int j = 0; j < 8; ++j) {
    bk[j] = bm1f[q * 8 + j];       bk[8 + j] = bm1f[32 + q * 8 + j];
    s1k[j] = s1[q * 8 + j];        s1k[8 + j] = s1[32 + q * 8 + j];
    t1k[j] = t1[q * 8 + j];        t1k[8 + j] = t1[32 + q * 8 + j];
  }
  bf16x8 b2h00, b2h01, b2h10, b2h11;
#pragma unroll
  for (int j = 0; j < 8; ++j) {
    b2h00[j] = (bf16_t)Wm2f[(q * 8 + j) * 32 + 0 * 16 + n];
    b2h01[j] = (bf16_t)Wm2f[(q * 8 + j) * 32 + 1 * 16 + n];
    b2h10[j] = (bf16_t)Wm2f[(32 + q * 8 + j) * 32 + 0 * 16 + n];
    b2h11[j] = (bf16_t)Wm2f[(32 + q * 8 + j) * 32 + 1 * 16 + n];
  }
  float bias20 = bm2f[n], bias21 = bm2f[16 + n];
  float s2c0 = s2[n], t2c0 = t2[n], s2c1 = s2[16 + n], t2c1 = t2[16 + n];
  float w3a0 = Wm3f[n * 2 + 0], w3a1 = Wm3f[n * 2 + 1];
  float w3b0 = Wm3f[(16 + n) * 2 + 0], w3b1 = Wm3f[(16 + n) * 2 + 1];
  float bb0 = bm3f[0], bb1 = bm3f[1];

  for (int t = wave; t < NE / 16; t += nwaves) {
    int e = t * 16 + n;
    int src = eic[e], dst = eic[NE + e];
    const bf16x8* pu = (const bf16x8*)(u + src * 64);
    const bf16x8* pv = (const bf16x8*)(v + dst * 64);
    bf16x8 ua = pu[q], ub = pu[4 + q], va = pv[q], vb = pv[4 + q];
    f32x16 a1k;
#pragma unroll
    for (int j = 0; j < 8; ++j) {
      a1k[j] = fmaxf((float)ua[j] + (float)va[j] + bk[j], 0.f);
      a1k[8 + j] = fmaxf((float)ub[j] + (float)vb[j] + bk[8 + j], 0.f);
    }
    f32x16 z = a1k * s1k + t1k;
    bf16x8 g0h, g0l, g1h, g1l;
#pragma unroll
    for (int j = 0; j < 8; ++j) {
      float z0 = z[j], z1 = z[8 + j];
      bf16_t h0 = (bf16_t)z0, h1 = (bf16_t)z1;
      g0h[j] = h0; g0l[j] = (bf16_t)(z0 - (float)h0);
      g1h[j] = h1; g1l[j] = (bf16_t)(z1 - (float)h1);
    }
    f32x4 c0 = {0.f, 0.f, 0.f, 0.f}, c1 = {0.f, 0.f, 0.f, 0.f};
    c0 = __builtin_amdgcn_mfma_f32_16x16x32_bf16(g0h, b2h00, c0, 0, 0, 0);
    c0 = __builtin_amdgcn_mfma_f32_16x16x32_bf16(g0l, b2h00, c0, 0, 0, 0);
    c0 = __builtin_amdgcn_mfma_f32_16x16x32_bf16(g1h, b2h10, c0, 0, 0, 0);
    c0 = __builtin_amdgcn_mfma_f32_16x16x32_bf16(g1l, b2h10, c0, 0, 0, 0);
    c1 = __builtin_amdgcn_mfma_f32_16x16x32_bf16(g0h, b2h01, c1, 0, 0, 0);
    c1 = __builtin_amdgcn_mfma_f32_16x16x32_bf16(g0l, b2h01, c1, 0, 0, 0);
    c1 = __builtin_amdgcn_mfma_f32_16x16x32_bf16(g1h, b2h11, c1, 0, 0, 0);
    c1 = __builtin_amdgcn_mfma_f32_16x16x32_bf16(g1l, b2h11, c1, 0, 0, 0);
#pragma unroll
    for (int r = 0; r < 4; ++r) {
      float z0 = fmaxf(c0[r] + bias20, 0.f) * s2c0 + t2c0;
      float z1 = fmaxf(c1[r] + bias21, 0.f) * s2c1 + t2c1;
      float o0 = z0 * w3a0 + z1 * w3b0;
      float o1 = z0 * w3a1 + z1 * w3b1;
      o0 += __shfl_xor(o0, 1); o0 += __shfl_xor(o0, 2);
      o0 += __shfl_xor(o0, 4); o0 += __shfl_xor(o0, 8);
      o1 += __shfl_xor(o1, 1); o1 += __shfl_xor(o1, 2);
      o1 += __shfl_xor(o1, 4); o1 += __shfl_xor(o1, 8);
      if (n == 0) {
        int eo = t * 16 + q * 4 + r;
        o0 += bb0; o1 += bb1;
        if (sizeof(OT) == 2) {
          bf16_t p[2] = {(bf16_t)o0, (bf16_t)o1};
          unsigned pw;
          memcpy(&pw, p, 4);
          ((unsigned*)out)[eo] = pw;
        } else {
          f32x2 pw = {o0, o1};
          ((f32x2*)out)[eo] = pw;
        }
      }
    }
  }
}

// ---------------- host ----------------
extern "C" void kernel_launch(void* const* d_in, const int* in_sizes, int n_in,
                              void* d_out, int out_size, void* d_ws, size_t ws_size,
                              hipStream_t stream) {
  (void)n_in; (void)in_sizes; (void)out_size;

  char* ws = (char*)d_ws;
  size_t off = 0;
  auto alloc = [&](size_t bytes) {
    size_t r = off;
    off = (off + bytes + 255) & ~(size_t)255;
    return r;
  };
  float* dinv  = (float*)(ws + alloc((size_t)NN * 4));
  float* hs    = (float*)(ws + alloc((size_t)NN * HID * 4));
  float* agg   = (float*)(ws + alloc((size_t)NN * HID * 4));  // hs3
  int*   eic   = (int*)(ws + alloc((size_t)2 * NE * 4));
  float* stats = (float*)(ws + alloc(192 * 4));
  float* sum1 = stats, *sq1 = stats + 64, *sum2 = stats + 128, *sq2 = stats + 160;
  int*   flags = (int*)(ws + alloc(256));
  float* s1arr = (float*)(ws + alloc(64 * 4));
  float* t1arr = (float*)(ws + alloc(64 * 4));
  float* s2arr = (float*)(ws + alloc(32 * 4));
  float* t2arr = (float*)(ws + alloc(32 * 4));
  // dst-CSR (GCN gather) + bucketed build
  int* cnt     = (int*)(ws + alloc((size_t)NN * 4));
  int* rowptr  = (int*)(ws + alloc((size_t)NN * 4));
  int* bsum    = (int*)(ws + alloc(512 * 4));
  int* btop    = (int*)(ws + alloc(512 * 4));
  int* bcnt    = (int*)(ws + alloc(NB1 * 4));
  int* bptr    = (int*)(ws + alloc(NB1 * 4));
  int* bcur    = (int*)(ws + alloc(NB1 * 4));
  int* csr_src = (int*)(ws + alloc((size_t)NE * 4));
  long long* staging = (long long*)(ws + alloc((size_t)NE * 8));
  // node-level MLP factors + 3-dim staging
  bf16_t* u    = (bf16_t*)(ws + alloc((size_t)NN * HID * 2));
  bf16_t* v    = (bf16_t*)(ws + alloc((size_t)NN * HID * 2));
  f32x4* xs4   = (f32x4*)(ws + alloc((size_t)NN * 16));
  f32x4* agg3  = (f32x4*)(ws + alloc((size_t)NN * 16));

  // canonical f32 input block
  static const int flens[17] = {NN * 3, 3 * 64, 64, 64 * 64, 64, 64 * 64, 64,
                                128 * 64, 64, 64, 64, 64 * 32, 32, 32, 32, 32 * 2, 2};
  FPtrs fp;
  int total_f = 0;
  {
    int fi = 0;
    for (int i = 0; i < 18; ++i) {
      if (i == 1) continue;
      fp.p[fi] = d_in[i];
      fp.len[fi] = flens[fi];
      fp.ofs[fi] = total_f;
      total_f += flens[fi];
      ++fi;
    }
  }
  float* canon = (float*)(ws + alloc((size_t)total_f * 4));
  size_t a2_off = alloc((size_t)NE * 32 * 2);
  bf16_t* a2s = (bf16_t*)(ws + a2_off);
  bool tierB = (a2_off + (size_t)NE * 32 * 2) <= ws_size;

  const float* xf   = canon + fp.ofs[0];
  const float* W1f  = canon + fp.ofs[1];
  const float* b1f  = canon + fp.ofs[2];
  const float* W2f  = canon + fp.ofs[3];
  const float* b2f  = canon + fp.ofs[4];
  const float* W3f  = canon + fp.ofs[5];
  const float* b3f  = canon + fp.ofs[6];
  const float* Wm1f = canon + fp.ofs[7];
  const float* bm1f = canon + fp.ofs[8];
  const float* g1f  = canon + fp.ofs[9];
  const float* be1f = canon + fp.ofs[10];
  const float* Wm2f = canon + fp.ofs[11];
  const float* bm2f = canon + fp.ofs[12];
  const float* g2f  = canon + fp.ofs[13];
  const float* be2f = canon + fp.ofs[14];
  const float* Wm3f = canon + fp.ofs[15];
  const float* bm3f = canon + fp.ofs[16];

  const int nscanb = (NN + 255) / 256;  // 391

  // 0) detect dtypes, canonicalize
  k_detect<<<1, 64, 0, stream>>>((const unsigned*)d_in[0], (const int*)d_in[1], flags);
  k_cvt_idx<int><<<1600, 256, 0, stream>>>((const int*)d_in[1], eic, flags);
  k_cvt_idx<long long><<<1600, 256, 0, stream>>>((const long long*)d_in[1], eic, flags);
  k_cvt_f<float><<<640, 256, 0, stream>>>(fp, canon, flags, total_f);
  k_cvt_f<bf16_t><<<640, 256, 0, stream>>>(fp, canon, flags, total_f);

  // 1) bucketed CSR build + dinv + stats zero
  k_zero4<<<128, 256, 0, stream>>>((f32x4*)cnt, NN / 4);
  k_zero4<<<1, 64, 0, stream>>>((f32x4*)stats, 48);
  k_zero4<<<1, 32, 0, stream>>>((f32x4*)bcnt, NB1 / 4);
  k_cnt2<<<200, 256, 0, stream>>>(eic + NE, cnt, bcnt);
  k_dinv<<<(NN + 255) / 256, 256, 0, stream>>>(cnt, dinv);
  k_scan1<<<nscanb, 256, 0, stream>>>(cnt, rowptr, bsum, NN);
  k_scan2<<<1, 512, 0, stream>>>(bsum, btop, nscanb);
  k_scan3<<<nscanb, 256, 0, stream>>>(rowptr, btop, NN);
  k_scanb<<<1, NB1, 0, stream>>>(bcnt, bptr, bcur);
  k_p1<<<(NE + 2047) / 2048, 256, 0, stream>>>(eic, bcur, staging);
  k_p2<<<NB1, 256, 0, stream>>>(staging, bptr, bcnt, rowptr, csr_src);

  // ---- GCN layer 1 (3-dim aggregation; aggregation commutes with @W1) ----
  k_xs<<<(NN + 255) / 256, 256, 0, stream>>>(xf, dinv, xs4);
  k_g1<<<2048, 256, 0, stream>>>(rowptr, cnt, csr_src, xs4, dinv, agg3);
  k_f1<<<1024, 512, 0, stream>>>(agg3, W1f, b1f, W2f, dinv, hs);  // hs2

  // ---- GCN layer 2 (gather + fused @W3*dinv; 8-wave blocks) ----
  k_g2<<<1024, 512, 0, stream>>>(rowptr, cnt, csr_src, hs, dinv, b2f, W3f, agg);  // hs3

  // ---- GCN layer 3 (gather + fused @Wm1 halves -> u,v; 8-wave blocks) ----
  k_g3<<<1024, 512, 0, stream>>>(rowptr, cnt, csr_src, agg, dinv, b3f, Wm1f, u, v);

  // ---- edge MLP ----
  k_e1<<<2048, 256, 0, stream>>>(eic, u, v, bm1f, sum1, sq1);
  k_bnconst<<<1, 64, 0, stream>>>(sum1, sq1, g1f, be1f, s1arr, t1arr, 64);
  if (tierB) {
    k_e2<true><<<2048, 256, 0, stream>>>(eic, u, v, bm1f, s1arr, t1arr, Wm2f, bm2f, a2s,
                                         sum2, sq2);
    k_bnconst<<<1, 64, 0, stream>>>(sum2, sq2, g2f, be2f, s2arr, t2arr, 32);
    k_out_stream<float><<<2048, 256, 0, stream>>>(a2s, s2arr, t2arr, Wm3f, bm3f,
                                                  (float*)d_out, flags);
    k_out_stream<bf16_t><<<2048, 256, 0, stream>>>(a2s, s2arr, t2arr, Wm3f, bm3f,
                                                   (bf16_t*)d_out, flags);
  } else {
    k_e2<false><<<2048, 256, 0, stream>>>(eic, u, v, bm1f, s1arr, t1arr, Wm2f, bm2f, a2s,
                                          sum2, sq2);
    k_bnconst<<<1, 64, 0, stream>>>(sum2, sq2, g2f, be2f, s2arr, t2arr, 32);
    k_out_recomp<float><<<2048, 256, 0, stream>>>(eic, u, v, bm1f, s1arr, t1arr, Wm2f,
                                                  bm2f, s2arr, t2arr, Wm3f, bm3f,
                                                  (float*)d_out, flags);
    k_out_recomp<bf16_t><<<2048, 256, 0, stream>>>(eic, u, v, bm1f, s1arr, t1arr, Wm2f,
                                                   bm2f, s2arr, t2arr, Wm3f, bm3f,
                                                   (bf16_t*)d_out, flags);
  }
}